// Round 15
// baseline (2305.886 us; speedup 1.0000x reference)
//
#include <hip/hip_runtime.h>
#include <cstddef>

#define BB   8
#define NN   2048
#define CIN  64
#define COUT 64
#define KK   20
#define KSS  20
#define C2   128   // 2*CIN

// ---------------------------------------------------------------------------
// Fused per-point kernel: KNN ranked in FP64 (matches a float64 np reference's
// top-20 membership; within-20 order is aggregation-invariant) + features +
// perm + agg + conv + mlp_out residual, fp32. grid = B*N blocks x 64 threads.
// OUTPUT: fp32, layout [B][COUT][N].
// ---------------------------------------------------------------------------
__global__ __launch_bounds__(64) void point_kernel(
    const float* __restrict__ x,
    const float* __restrict__ feature,
    const float* __restrict__ kern,
    const float* __restrict__ pad,
    const float* __restrict__ mlp_w,
    const float* __restrict__ mlp_b,
    const float* __restrict__ conv_w,
    const float* __restrict__ conv_b,
    const float* __restrict__ mow,
    const float* __restrict__ mob,
    float* __restrict__ out)
{
    __shared__ double d2s[NN];          // 16 KB (fp64 exact ranking)
    __shared__ float feats[C2][KK];
    __shared__ float agg[C2 * KSS];
    __shared__ float perm[KK][KSS];
    __shared__ float xr[KK][3];
    __shared__ float xd[KK];
    __shared__ float xrep[3];
    __shared__ float colden[KSS];
    __shared__ int   nid[KK];

    const int t = threadIdx.x;
    const int p = blockIdx.x;
    const int b = p >> 11;
    const int n = p & (NN - 1);

    const float* xb0 = x + (size_t)(b * 3 + 0) * NN;
    const float* xb1 = x + (size_t)(b * 3 + 1) * NN;
    const float* xb2 = x + (size_t)(b * 3 + 2) * NN;

    // ---- d2 in fp64 (exact for fp32 inputs; self-d2 == 0 exactly) ----
    const double qx = (double)xb0[n], qy = (double)xb1[n], qz = (double)xb2[n];
    const double qs = qx * qx + qy * qy + qz * qz;
    for (int m = t; m < NN; m += 64) {
        double dx = (double)xb0[m], dy = (double)xb1[m], dz = (double)xb2[m];
        double sm  = dx * dx + dy * dy + dz * dz;
        double dot = qx * dx + qy * dy + qz * dz;
        d2s[m] = qs + sm - 2.0 * dot;
    }
    __syncthreads();

    // ---- stable top-KK smallest: 20 rounds of lexicographic argmin ----
    for (int k = 0; k < KK; ++k) {
        double bd = 1e300; int bm = 0;
        for (int m = t; m < NN; m += 64) {      // ascending m + strict < => stable
            double v = d2s[m];
            if (v < bd) { bd = v; bm = m; }
        }
        for (int off = 32; off > 0; off >>= 1) {
            double od = __shfl_down(bd, off);
            int   om  = __shfl_down(bm, off);
            if (od < bd || (od == bd && om < bm)) { bd = od; bm = om; }
        }
        if (t == 0) { nid[k] = bm; d2s[bm] = 1e300; }
        __syncthreads();
    }

    // ---- x_repeat, x_rel, x_dis (fp32, as reference) ----
    if (t == 0) {
        int m0 = nid[0];
        xrep[0] = xb0[m0]; xrep[1] = xb1[m0]; xrep[2] = xb2[m0];
    }
    __syncthreads();
    if (t < KK) {
        int m = nid[t];
        float rx = xb0[m] - xrep[0];
        float ry = xb1[m] - xrep[1];
        float rz = xb2[m] - xrep[2];
        xr[t][0] = rx; xr[t][1] = ry; xr[t][2] = rz;
        xd[t] = sqrtf(rx * rx + ry * ry + rz * rz + 1e-12f);
    }
    __syncthreads();

    // ---- perm: relu -> colnorm -> square -> colnorm -> >0.1 ----
    for (int e = t; e < KK * KSS; e += 64) {
        int k = e / KSS, m = e % KSS;
        float v = xr[k][0] * kern[0 * KSS + m]
                + xr[k][1] * kern[1 * KSS + m]
                + xr[k][2] * kern[2 * KSS + m]
                + pad[k * KSS + m];
        perm[k][m] = v > 0.0f ? v : 0.0f;
    }
    __syncthreads();
    if (t < KSS) {
        float s = 0.0f;
        for (int k = 0; k < KK; ++k) s += perm[k][t];
        colden[t] = s + 1e-6f;
    }
    __syncthreads();
    for (int e = t; e < KK * KSS; e += 64) {
        int k = e / KSS, m = e % KSS;
        float v = perm[k][m] / colden[m];
        perm[k][m] = v * v;
    }
    __syncthreads();
    if (t < KSS) {
        float s = 0.0f;
        for (int k = 0; k < KK; ++k) s += perm[k][t];
        colden[t] = s + 1e-6f;
    }
    __syncthreads();
    for (int e = t; e < KK * KSS; e += 64) {
        int k = e / KSS, m = e % KSS;
        float v = perm[k][m] / colden[m];
        perm[k][m] = v > 0.1f ? v : 0.0f;
    }
    __syncthreads();

    // ---- feats ----
    for (int e = t; e < CIN * KK; e += 64) {
        int c = e / KK, k = e % KK;
        feats[c][k] = feature[(size_t)(b * CIN + c) * NN + nid[k]];
    }
    {
        float w0 = mlp_w[t * 7 + 0], w1 = mlp_w[t * 7 + 1];
        float w2 = mlp_w[t * 7 + 2], w3 = mlp_w[t * 7 + 3];
        float w4 = mlp_w[t * 7 + 4], w5 = mlp_w[t * 7 + 5];
        float w6 = mlp_w[t * 7 + 6];
        float bias = mlp_b[t];
        for (int k = 0; k < KK; ++k) {
            feats[CIN + t][k] = xrep[0] * w0 + xrep[1] * w1 + xrep[2] * w2
                              + xr[k][0] * w3 + xr[k][1] * w4 + xr[k][2] * w5
                              + xd[k] * w6 + bias;
        }
    }
    __syncthreads();

    // ---- agg[c][m] = sum_k feats[c][k] * perm[k][m] ----
    for (int e = t; e < C2 * KSS; e += 64) {
        int c = e / KSS, m = e % KSS;
        float s = 0.0f;
        for (int k = 0; k < KK; ++k) s += feats[c][k] * perm[k][m];
        agg[e] = s;
    }
    __syncthreads();

    // ---- conv + mlp_out residual; fp32 store at [b][t][n] ----
    {
        float acc = conv_b[t];
        const float4* wr = (const float4*)(conv_w + (size_t)t * (C2 * KSS));
        for (int j4 = 0; j4 < (C2 * KSS) / 4; ++j4) {
            float4 u = wr[j4];
            int j = j4 * 4;
            acc += u.x * agg[j + 0];
            acc += u.y * agg[j + 1];
            acc += u.z * agg[j + 2];
            acc += u.w * agg[j + 3];
        }
        for (int c = 0; c < CIN; ++c)
            acc += feature[(size_t)(b * CIN + c) * NN + n] * mow[t * CIN + c];
        acc += mob[t];
        out[(size_t)(b * COUT + t) * NN + n] = acc;   // fp32, [B][C][N]
    }
}

// ---------------------------------------------------------------------------
// BatchNorm per channel over (B,N), fp32 in-place. 64 blocks x 256.
// ---------------------------------------------------------------------------
__global__ __launch_bounds__(256) void bn_kernel(
    float* __restrict__ out,
    const float* __restrict__ gamma,
    const float* __restrict__ beta)
{
    const int o = blockIdx.x;
    __shared__ float s1[256], s2[256];
    __shared__ float mean_s, inv_s;

    float a = 0.0f, q = 0.0f;
    for (int i = threadIdx.x; i < BB * NN; i += 256) {
        int b = i >> 11, n = i & (NN - 1);
        float v = out[(size_t)(b * COUT + o) * NN + n];
        a += v; q += v * v;
    }
    s1[threadIdx.x] = a; s2[threadIdx.x] = q;
    __syncthreads();
    for (int s = 128; s > 0; s >>= 1) {
        if (threadIdx.x < s) {
            s1[threadIdx.x] += s1[threadIdx.x + s];
            s2[threadIdx.x] += s2[threadIdx.x + s];
        }
        __syncthreads();
    }
    if (threadIdx.x == 0) {
        const float M = (float)(BB * NN);
        float mean = s1[0] / M;
        float var  = s2[0] / M - mean * mean;
        if (var < 0.0f) var = 0.0f;
        mean_s = mean;
        inv_s  = 1.0f / sqrtf(var + 1e-5f);
    }
    __syncthreads();
    const float mean = mean_s, inv = inv_s;
    const float g = gamma[o], be = beta[o];
    for (int i = threadIdx.x; i < BB * NN; i += 256) {
        int b = i >> 11, n = i & (NN - 1);
        size_t ad = (size_t)(b * COUT + o) * NN + n;
        out[ad] = (out[ad] - mean) * inv * g + be;
    }
}

// ---------------------------------------------------------------------------
extern "C" void kernel_launch(void* const* d_in, const int* in_sizes, int n_in,
                              void* d_out, int out_size, void* d_ws, size_t ws_size,
                              hipStream_t stream)
{
    const float* x       = (const float*)d_in[0];
    const float* feature = (const float*)d_in[1];
    const float* kern    = (const float*)d_in[2];
    const float* pad     = (const float*)d_in[3];
    const float* mlp_w   = (const float*)d_in[4];
    const float* mlp_b   = (const float*)d_in[5];
    const float* conv_w  = (const float*)d_in[6];
    const float* conv_b  = (const float*)d_in[7];
    const float* mow     = (const float*)d_in[8];
    const float* mob     = (const float*)d_in[9];
    const float* gamma   = (const float*)d_in[10];
    const float* beta    = (const float*)d_in[11];

    float* out = (float*)d_out;

    point_kernel<<<BB * NN, 64, 0, stream>>>(x, feature, kern, pad, mlp_w, mlp_b,
                                             conv_w, conv_b, mow, mob, out);
    bn_kernel<<<COUT, 256, 0, stream>>>(out, gamma, beta);
}

// Round 16
// 975.248 us; speedup vs baseline: 2.3644x; 2.3644x over previous
//
#include <hip/hip_runtime.h>
#include <cstddef>

#define BB   8
#define NN   2048
#define CIN  64
#define COUT 64
#define KK   20
#define KSS  20
#define C2   128   // 2*CIN
#define NJ4  (C2 * KSS / 4)   // 640 float4 rows of the conv matrix

// ---------------------------------------------------------------------------
// Prep: wT4[j4*64 + t] = float4(conv_w[t][4*j4 .. 4*j4+3])  (coalesced conv)
// ---------------------------------------------------------------------------
__global__ __launch_bounds__(256) void prep_kernel(
    const float* __restrict__ cw, float4* __restrict__ wT4)
{
    int i = blockIdx.x * 256 + threadIdx.x;          // NJ4*64 = 40960 total
    if (i < NJ4 * COUT) {
        int j4 = i >> 6, t = i & 63;
        const float* s = cw + (size_t)t * (C2 * KSS) + j4 * 4;
        wT4[i] = make_float4(s[0], s[1], s[2], s[3]);
    }
}

// ---------------------------------------------------------------------------
// KNN: one wave per query; fp64 d2 (exact membership ranking, matches the
// float64 np reference); 20 stable argmin rounds. Writes ushort idx to ws.
// LDS = 16.4 KB -> ~9 blocks/CU.
// ---------------------------------------------------------------------------
__global__ __launch_bounds__(64) void knn_kernel(
    const float* __restrict__ x, unsigned short* __restrict__ idx_out)
{
    __shared__ double d2s[NN];          // 16 KB
    __shared__ int nid[KK];

    const int t = threadIdx.x;
    const int p = blockIdx.x;
    const int b = p >> 11;
    const int n = p & (NN - 1);

    const float* xb0 = x + (size_t)(b * 3 + 0) * NN;
    const float* xb1 = x + (size_t)(b * 3 + 1) * NN;
    const float* xb2 = x + (size_t)(b * 3 + 2) * NN;

    const double qx = (double)xb0[n], qy = (double)xb1[n], qz = (double)xb2[n];
    for (int m = t; m < NN; m += 64) {
        double dx = (double)xb0[m] - qx;
        double dy = (double)xb1[m] - qy;
        double dz = (double)xb2[m] - qz;
        d2s[m] = dx * dx + dy * dy + dz * dz;    // exact-ranking equivalent
    }
    __syncthreads();

    for (int k = 0; k < KK; ++k) {
        double bd = 1e300; int bm = 0;
        for (int m = t; m < NN; m += 64) {       // ascending m + strict < => stable
            double v = d2s[m];
            if (v < bd) { bd = v; bm = m; }
        }
        for (int off = 32; off > 0; off >>= 1) {
            double od = __shfl_down(bd, off);
            int   om  = __shfl_down(bm, off);
            if (od < bd || (od == bd && om < bm)) { bd = od; bm = om; }
        }
        if (t == 0) { nid[k] = bm; d2s[bm] = 1e300; }
        __syncthreads();
    }
    if (t < KK) idx_out[(size_t)p * KK + t] = (unsigned short)nid[t];
}

// ---------------------------------------------------------------------------
// Per-point: features + perm + agg + conv (coalesced wT4) + residual.
// LDS ~22.6 KB -> ~7 blocks/CU. fp32 out [B][COUT][N].
// ---------------------------------------------------------------------------
__global__ __launch_bounds__(64) void point_kernel(
    const float* __restrict__ x,
    const float* __restrict__ feature,
    const float* __restrict__ kern,
    const float* __restrict__ pad,
    const float* __restrict__ mlp_w,
    const float* __restrict__ mlp_b,
    const float4* __restrict__ wT4,
    const float* __restrict__ conv_b,
    const float* __restrict__ mow,
    const float* __restrict__ mob,
    const unsigned short* __restrict__ idx,
    float* __restrict__ out)
{
    __shared__ float feats[C2][KK];                 // 10240 B
    __shared__ __align__(16) float agg[C2 * KSS];   // 10240 B
    __shared__ float perm[KK][KSS];
    __shared__ float xr[KK][3];
    __shared__ float xd[KK];
    __shared__ float xrep[3];
    __shared__ float colden[KSS];
    __shared__ int   nid[KK];

    const int t = threadIdx.x;
    const int p = blockIdx.x;
    const int b = p >> 11;
    const int n = p & (NN - 1);

    const float* xb0 = x + (size_t)(b * 3 + 0) * NN;
    const float* xb1 = x + (size_t)(b * 3 + 1) * NN;
    const float* xb2 = x + (size_t)(b * 3 + 2) * NN;

    if (t < KK) nid[t] = (int)idx[(size_t)p * KK + t];
    __syncthreads();

    if (t == 0) {
        int m0 = nid[0];
        xrep[0] = xb0[m0]; xrep[1] = xb1[m0]; xrep[2] = xb2[m0];
    }
    __syncthreads();
    if (t < KK) {
        int m = nid[t];
        float rx = xb0[m] - xrep[0];
        float ry = xb1[m] - xrep[1];
        float rz = xb2[m] - xrep[2];
        xr[t][0] = rx; xr[t][1] = ry; xr[t][2] = rz;
        xd[t] = sqrtf(rx * rx + ry * ry + rz * rz + 1e-12f);
    }
    __syncthreads();

    // ---- perm: relu -> colnorm -> square -> colnorm -> >0.1 ----
    for (int e = t; e < KK * KSS; e += 64) {
        int k = e / KSS, m = e % KSS;
        float v = xr[k][0] * kern[0 * KSS + m]
                + xr[k][1] * kern[1 * KSS + m]
                + xr[k][2] * kern[2 * KSS + m]
                + pad[k * KSS + m];
        perm[k][m] = v > 0.0f ? v : 0.0f;
    }
    __syncthreads();
    if (t < KSS) {
        float s = 0.0f;
        for (int k = 0; k < KK; ++k) s += perm[k][t];
        colden[t] = s + 1e-6f;
    }
    __syncthreads();
    for (int e = t; e < KK * KSS; e += 64) {
        int k = e / KSS, m = e % KSS;
        float v = perm[k][m] / colden[m];
        perm[k][m] = v * v;
    }
    __syncthreads();
    if (t < KSS) {
        float s = 0.0f;
        for (int k = 0; k < KK; ++k) s += perm[k][t];
        colden[t] = s + 1e-6f;
    }
    __syncthreads();
    for (int e = t; e < KK * KSS; e += 64) {
        int k = e / KSS, m = e % KSS;
        float v = perm[k][m] / colden[m];
        perm[k][m] = v > 0.1f ? v : 0.0f;
    }
    __syncthreads();

    // ---- feats ----
    for (int e = t; e < CIN * KK; e += 64) {
        int c = e / KK, k = e % KK;
        feats[c][k] = feature[(size_t)(b * CIN + c) * NN + nid[k]];
    }
    {
        float w0 = mlp_w[t * 7 + 0], w1 = mlp_w[t * 7 + 1];
        float w2 = mlp_w[t * 7 + 2], w3 = mlp_w[t * 7 + 3];
        float w4 = mlp_w[t * 7 + 4], w5 = mlp_w[t * 7 + 5];
        float w6 = mlp_w[t * 7 + 6];
        float bias = mlp_b[t];
        for (int k = 0; k < KK; ++k) {
            feats[CIN + t][k] = xrep[0] * w0 + xrep[1] * w1 + xrep[2] * w2
                              + xr[k][0] * w3 + xr[k][1] * w4 + xr[k][2] * w5
                              + xd[k] * w6 + bias;
        }
    }
    __syncthreads();

    // ---- agg[c][m] = sum_k feats[c][k] * perm[k][m] ----
    for (int e = t; e < C2 * KSS; e += 64) {
        int c = e / KSS, m = e % KSS;
        float s = 0.0f;
        for (int k = 0; k < KK; ++k) s += feats[c][k] * perm[k][m];
        agg[e] = s;
    }
    __syncthreads();

    // ---- conv (coalesced wT4) + mlp_out residual; fp32 store [b][t][n] ----
    {
        float acc = conv_b[t];
        const float4* wp = wT4 + t;
#pragma unroll 4
        for (int j4 = 0; j4 < NJ4; ++j4) {
            float4 w = wp[(size_t)j4 * 64];                 // coalesced 1 KB/instr
            float4 a = *(const float4*)(agg + j4 * 4);      // LDS broadcast b128
            acc += w.x * a.x;
            acc += w.y * a.y;
            acc += w.z * a.z;
            acc += w.w * a.w;
        }
        for (int c = 0; c < CIN; ++c)
            acc += feature[(size_t)(b * CIN + c) * NN + n] * mow[t * CIN + c];
        acc += mob[t];
        out[(size_t)(b * COUT + t) * NN + n] = acc;
    }
}

// ---------------------------------------------------------------------------
// BatchNorm per channel over (B,N), fp32 in-place. 64 blocks x 256.
// ---------------------------------------------------------------------------
__global__ __launch_bounds__(256) void bn_kernel(
    float* __restrict__ out,
    const float* __restrict__ gamma,
    const float* __restrict__ beta)
{
    const int o = blockIdx.x;
    __shared__ float s1[256], s2[256];
    __shared__ float mean_s, inv_s;

    float a = 0.0f, q = 0.0f;
    for (int i = threadIdx.x; i < BB * NN; i += 256) {
        int b = i >> 11, n = i & (NN - 1);
        float v = out[(size_t)(b * COUT + o) * NN + n];
        a += v; q += v * v;
    }
    s1[threadIdx.x] = a; s2[threadIdx.x] = q;
    __syncthreads();
    for (int s = 128; s > 0; s >>= 1) {
        if (threadIdx.x < s) {
            s1[threadIdx.x] += s1[threadIdx.x + s];
            s2[threadIdx.x] += s2[threadIdx.x + s];
        }
        __syncthreads();
    }
    if (threadIdx.x == 0) {
        const float M = (float)(BB * NN);
        float mean = s1[0] / M;
        float var  = s2[0] / M - mean * mean;
        if (var < 0.0f) var = 0.0f;
        mean_s = mean;
        inv_s  = 1.0f / sqrtf(var + 1e-5f);
    }
    __syncthreads();
    const float mean = mean_s, inv = inv_s;
    const float g = gamma[o], be = beta[o];
    for (int i = threadIdx.x; i < BB * NN; i += 256) {
        int b = i >> 11, n = i & (NN - 1);
        size_t ad = (size_t)(b * COUT + o) * NN + n;
        out[ad] = (out[ad] - mean) * inv * g + be;
    }
}

// ---------------------------------------------------------------------------
extern "C" void kernel_launch(void* const* d_in, const int* in_sizes, int n_in,
                              void* d_out, int out_size, void* d_ws, size_t ws_size,
                              hipStream_t stream)
{
    const float* x       = (const float*)d_in[0];
    const float* feature = (const float*)d_in[1];
    const float* kern    = (const float*)d_in[2];
    const float* pad     = (const float*)d_in[3];
    const float* mlp_w   = (const float*)d_in[4];
    const float* mlp_b   = (const float*)d_in[5];
    const float* conv_w  = (const float*)d_in[6];
    const float* conv_b  = (const float*)d_in[7];
    const float* mow     = (const float*)d_in[8];
    const float* mob     = (const float*)d_in[9];
    const float* gamma   = (const float*)d_in[10];
    const float* beta    = (const float*)d_in[11];

    float4*         wT4     = (float4*)d_ws;                         // 655360 B
    unsigned short* idx_buf = (unsigned short*)((char*)d_ws + 655360); // 655360 B

    float* out = (float*)d_out;

    prep_kernel<<<(NJ4 * COUT + 255) / 256, 256, 0, stream>>>(conv_w, wT4);
    knn_kernel<<<BB * NN, 64, 0, stream>>>(x, idx_buf);
    point_kernel<<<BB * NN, 64, 0, stream>>>(x, feature, kern, pad, mlp_w, mlp_b,
                                             wT4, conv_b, mow, mob, idx_buf, out);
    bn_kernel<<<COUT, 256, 0, stream>>>(out, gamma, beta);
}

// Round 17
// 850.630 us; speedup vs baseline: 2.7108x; 1.1465x over previous
//
#include <hip/hip_runtime.h>
#include <cstddef>

#define BB   8
#define NN   2048
#define CIN  64
#define COUT 64
#define KK   20
#define KSS  20
#define C2   128   // 2*CIN
#define NJ4  (C2 * KSS / 4)   // 640 float4 rows of the conv matrix
#define PPB  4                 // points per block

// ---------------------------------------------------------------------------
// Prep: wT4[j4*64 + t] = float4(conv_w[t][4*j4..]); mowT[c*64 + o] = mow[o][c]
// ---------------------------------------------------------------------------
__global__ __launch_bounds__(256) void prep_kernel(
    const float* __restrict__ cw, const float* __restrict__ mw,
    float4* __restrict__ wT4, float* __restrict__ mowT)
{
    int i = blockIdx.x * 256 + threadIdx.x;
    if (i < NJ4 * COUT) {
        int j4 = i >> 6, t = i & 63;
        const float* s = cw + (size_t)t * (C2 * KSS) + j4 * 4;
        wT4[i] = make_float4(s[0], s[1], s[2], s[3]);
    }
    if (i < COUT * CIN) {
        int o = i >> 6, c = i & 63;
        mowT[c * COUT + o] = mw[o * CIN + c];
    }
}

// ---------------------------------------------------------------------------
// KNN (unchanged, verified): one wave per query, fp64 exact membership.
// ---------------------------------------------------------------------------
__global__ __launch_bounds__(64) void knn_kernel(
    const float* __restrict__ x, unsigned short* __restrict__ idx_out)
{
    __shared__ double d2s[NN];
    __shared__ int nid[KK];

    const int t = threadIdx.x;
    const int p = blockIdx.x;
    const int b = p >> 11;
    const int n = p & (NN - 1);

    const float* xb0 = x + (size_t)(b * 3 + 0) * NN;
    const float* xb1 = x + (size_t)(b * 3 + 1) * NN;
    const float* xb2 = x + (size_t)(b * 3 + 2) * NN;

    const double qx = (double)xb0[n], qy = (double)xb1[n], qz = (double)xb2[n];
    for (int m = t; m < NN; m += 64) {
        double dx = (double)xb0[m] - qx;
        double dy = (double)xb1[m] - qy;
        double dz = (double)xb2[m] - qz;
        d2s[m] = dx * dx + dy * dy + dz * dz;
    }
    __syncthreads();

    for (int k = 0; k < KK; ++k) {
        double bd = 1e300; int bm = 0;
        for (int m = t; m < NN; m += 64) {
            double v = d2s[m];
            if (v < bd) { bd = v; bm = m; }
        }
        for (int off = 32; off > 0; off >>= 1) {
            double od = __shfl_down(bd, off);
            int   om  = __shfl_down(bm, off);
            if (od < bd || (od == bd && om < bm)) { bd = od; bm = om; }
        }
        if (t == 0) { nid[k] = bm; d2s[bm] = 1e300; }
        __syncthreads();
    }
    if (t < KK) idx_out[(size_t)p * KK + t] = (unsigned short)nid[t];
}

// ---------------------------------------------------------------------------
// Per-point stage, 4 points/block (wave w <-> point w). feats in REGISTERS,
// agg in LDS; conv reads coalesced wT4 shared by 4 waves. ~50 KB LDS.
// ---------------------------------------------------------------------------
__global__ __launch_bounds__(256, 3) void point_kernel(
    const float* __restrict__ x,
    const float* __restrict__ feature,
    const float* __restrict__ kern,
    const float* __restrict__ pad,
    const float* __restrict__ mlp_w,
    const float* __restrict__ mlp_b,
    const float4* __restrict__ wT4,
    const float* __restrict__ conv_b,
    const float* __restrict__ mowT,
    const float* __restrict__ mob,
    const unsigned short* __restrict__ idx,
    float* __restrict__ out)
{
    __shared__ __align__(16) float agg_s[PPB][C2 * KSS];   // 40960 B
    __shared__ float perm_s[PPB][KK][KSS];                 // 6400 B
    __shared__ float xr_s[PPB][KK][3];
    __shared__ float xd_s[PPB][KK];
    __shared__ float xrep_s[PPB][3];
    __shared__ float colden_s[PPB][KSS];
    __shared__ float fcol_s[PPB][CIN];
    __shared__ int   nid_s[PPB][KK];

    const int tid  = threadIdx.x;
    const int w    = tid >> 6;          // wave = point slot
    const int lane = tid & 63;
    const int p    = blockIdx.x * PPB + w;
    const int b    = p >> 11;
    const int n    = p & (NN - 1);

    const float* xb0 = x + (size_t)(b * 3 + 0) * NN;
    const float* xb1 = x + (size_t)(b * 3 + 1) * NN;
    const float* xb2 = x + (size_t)(b * 3 + 2) * NN;

    if (lane < KK) nid_s[w][lane] = (int)idx[(size_t)p * KK + lane];
    if (lane < CIN) fcol_s[w][lane] = feature[(size_t)(b * CIN + lane) * NN + n];
    __syncthreads();

    if (lane == 0) {
        int m0 = nid_s[w][0];
        xrep_s[w][0] = xb0[m0]; xrep_s[w][1] = xb1[m0]; xrep_s[w][2] = xb2[m0];
    }
    __syncthreads();
    if (lane < KK) {
        int m = nid_s[w][lane];
        float rx = xb0[m] - xrep_s[w][0];
        float ry = xb1[m] - xrep_s[w][1];
        float rz = xb2[m] - xrep_s[w][2];
        xr_s[w][lane][0] = rx; xr_s[w][lane][1] = ry; xr_s[w][lane][2] = rz;
        xd_s[w][lane] = sqrtf(rx * rx + ry * ry + rz * rz + 1e-12f);
    }
    __syncthreads();

    // ---- perm: relu -> colnorm -> square -> colnorm -> >0.1 ----
    for (int e = lane; e < KK * KSS; e += 64) {
        int k = e / KSS, m = e % KSS;
        float v = xr_s[w][k][0] * kern[0 * KSS + m]
                + xr_s[w][k][1] * kern[1 * KSS + m]
                + xr_s[w][k][2] * kern[2 * KSS + m]
                + pad[k * KSS + m];
        perm_s[w][k][m] = v > 0.0f ? v : 0.0f;
    }
    __syncthreads();
    if (lane < KSS) {
        float s = 0.0f;
        for (int k = 0; k < KK; ++k) s += perm_s[w][k][lane];
        colden_s[w][lane] = s + 1e-6f;
    }
    __syncthreads();
    for (int e = lane; e < KK * KSS; e += 64) {
        int k = e / KSS, m = e % KSS;
        float v = perm_s[w][k][m] / colden_s[w][m];
        perm_s[w][k][m] = v * v;
    }
    __syncthreads();
    if (lane < KSS) {
        float s = 0.0f;
        for (int k = 0; k < KK; ++k) s += perm_s[w][k][lane];
        colden_s[w][lane] = s + 1e-6f;
    }
    __syncthreads();
    for (int e = lane; e < KK * KSS; e += 64) {
        int k = e / KSS, m = e % KSS;
        float v = perm_s[w][k][m] / colden_s[w][m];
        perm_s[w][k][m] = v > 0.1f ? v : 0.0f;
    }
    __syncthreads();

    // ---- feats in registers: fg = gathered channel `lane`, fm = mlp ch ----
    float fg[KK], fm[KK];
#pragma unroll
    for (int k = 0; k < KK; ++k)
        fg[k] = feature[(size_t)(b * CIN + lane) * NN + nid_s[w][k]];
    {
        float w0 = mlp_w[lane * 7 + 0], w1 = mlp_w[lane * 7 + 1];
        float w2 = mlp_w[lane * 7 + 2], w3 = mlp_w[lane * 7 + 3];
        float w4 = mlp_w[lane * 7 + 4], w5 = mlp_w[lane * 7 + 5];
        float w6 = mlp_w[lane * 7 + 6];
        float bias = mlp_b[lane];
#pragma unroll
        for (int k = 0; k < KK; ++k) {
            fm[k] = xrep_s[w][0] * w0 + xrep_s[w][1] * w1 + xrep_s[w][2] * w2
                  + xr_s[w][k][0] * w3 + xr_s[w][k][1] * w4 + xr_s[w][k][2] * w5
                  + xd_s[w][k] * w6 + bias;
        }
    }

    // ---- agg rows c=lane and c=64+lane (k ascending: bit-matches prior) ----
#pragma unroll
    for (int m = 0; m < KSS; ++m) {
        float s = 0.0f, s2 = 0.0f;
#pragma unroll
        for (int k = 0; k < KK; ++k) {
            float pv = perm_s[w][k][m];
            s  += fg[k] * pv;
            s2 += fm[k] * pv;
        }
        agg_s[w][lane * KSS + m]         = s;
        agg_s[w][(CIN + lane) * KSS + m] = s2;
    }
    __syncthreads();

    // ---- conv (coalesced wT4, shared by 4 waves) + residual ----
    {
        float acc = conv_b[lane];
        const float4* wp = wT4 + lane;
#pragma unroll 4
        for (int j4 = 0; j4 < NJ4; ++j4) {
            float4 wv = wp[(size_t)j4 * 64];                   // 1 KB coalesced
            float4 a  = *(const float4*)(&agg_s[w][j4 * 4]);   // LDS broadcast
            acc += wv.x * a.x;
            acc += wv.y * a.y;
            acc += wv.z * a.z;
            acc += wv.w * a.w;
        }
        for (int c = 0; c < CIN; ++c)
            acc += fcol_s[w][c] * mowT[c * COUT + lane];       // coalesced
        acc += mob[lane];
        out[(size_t)(b * COUT + lane) * NN + n] = acc;
    }
}

// ---------------------------------------------------------------------------
// BatchNorm per channel over (B,N), fp32 in-place. 64 blocks x 256.
// ---------------------------------------------------------------------------
__global__ __launch_bounds__(256) void bn_kernel(
    float* __restrict__ out,
    const float* __restrict__ gamma,
    const float* __restrict__ beta)
{
    const int o = blockIdx.x;
    __shared__ float s1[256], s2[256];
    __shared__ float mean_s, inv_s;

    float a = 0.0f, q = 0.0f;
    for (int i = threadIdx.x; i < BB * NN; i += 256) {
        int b = i >> 11, n = i & (NN - 1);
        float v = out[(size_t)(b * COUT + o) * NN + n];
        a += v; q += v * v;
    }
    s1[threadIdx.x] = a; s2[threadIdx.x] = q;
    __syncthreads();
    for (int s = 128; s > 0; s >>= 1) {
        if (threadIdx.x < s) {
            s1[threadIdx.x] += s1[threadIdx.x + s];
            s2[threadIdx.x] += s2[threadIdx.x + s];
        }
        __syncthreads();
    }
    if (threadIdx.x == 0) {
        const float M = (float)(BB * NN);
        float mean = s1[0] / M;
        float var  = s2[0] / M - mean * mean;
        if (var < 0.0f) var = 0.0f;
        mean_s = mean;
        inv_s  = 1.0f / sqrtf(var + 1e-5f);
    }
    __syncthreads();
    const float mean = mean_s, inv = inv_s;
    const float g = gamma[o], be = beta[o];
    for (int i = threadIdx.x; i < BB * NN; i += 256) {
        int b = i >> 11, n = i & (NN - 1);
        size_t ad = (size_t)(b * COUT + o) * NN + n;
        out[ad] = (out[ad] - mean) * inv * g + be;
    }
}

// ---------------------------------------------------------------------------
extern "C" void kernel_launch(void* const* d_in, const int* in_sizes, int n_in,
                              void* d_out, int out_size, void* d_ws, size_t ws_size,
                              hipStream_t stream)
{
    const float* x       = (const float*)d_in[0];
    const float* feature = (const float*)d_in[1];
    const float* kern    = (const float*)d_in[2];
    const float* pad     = (const float*)d_in[3];
    const float* mlp_w   = (const float*)d_in[4];
    const float* mlp_b   = (const float*)d_in[5];
    const float* conv_w  = (const float*)d_in[6];
    const float* conv_b  = (const float*)d_in[7];
    const float* mow     = (const float*)d_in[8];
    const float* mob     = (const float*)d_in[9];
    const float* gamma   = (const float*)d_in[10];
    const float* beta    = (const float*)d_in[11];

    float4*         wT4     = (float4*)d_ws;                           // 655360 B
    unsigned short* idx_buf = (unsigned short*)((char*)d_ws + 655360); // 655360 B
    float*          mowT    = (float*)((char*)d_ws + 655360 * 2);      //  16384 B

    float* out = (float*)d_out;

    prep_kernel<<<(NJ4 * COUT + 255) / 256, 256, 0, stream>>>(conv_w, mow, wT4, mowT);
    knn_kernel<<<BB * NN, 64, 0, stream>>>(x, idx_buf);
    point_kernel<<<BB * NN / PPB, 256, 0, stream>>>(x, feature, kern, pad,
                                                    mlp_w, mlp_b, wT4, conv_b,
                                                    mowT, mob, idx_buf, out);
    bn_kernel<<<COUT, 256, 0, stream>>>(out, gamma, beta);
}

// Round 18
// 668.439 us; speedup vs baseline: 3.4497x; 1.2726x over previous
//
#include <hip/hip_runtime.h>
#include <cstddef>

#define BB   8
#define NN   2048
#define CIN  64
#define COUT 64
#define KK   20
#define KSS  20
#define C2   128   // 2*CIN
#define NJ4  (C2 * KSS / 4)   // 640 float4 rows of the conv matrix
#define PPB  4                 // points per block (point_kernel)

// ---------------------------------------------------------------------------
// Prep: wT4[j4*64 + t] = conv_w[t][4*j4..+3]; mowT[c*64 + o] = mow[o][c]
// ---------------------------------------------------------------------------
__global__ __launch_bounds__(256) void prep_kernel(
    const float* __restrict__ cw, const float* __restrict__ mw,
    float4* __restrict__ wT4, float* __restrict__ mowT)
{
    int i = blockIdx.x * 256 + threadIdx.x;
    if (i < NJ4 * COUT) {
        int j4 = i >> 6, t = i & 63;
        const float* s = cw + (size_t)t * (C2 * KSS) + j4 * 4;
        wT4[i] = make_float4(s[0], s[1], s[2], s[3]);
    }
    if (i < COUT * CIN) {
        int o = i >> 6, c = i & 63;
        mowT[c * COUT + o] = mw[o * CIN + c];
    }
}

// ---------------------------------------------------------------------------
// Transpose feature [B][C][N] -> featT [B][N][C], LDS-tiled 64x64.
// grid = B*32 blocks x 256 threads.
// ---------------------------------------------------------------------------
__global__ __launch_bounds__(256) void transpose_kernel(
    const float* __restrict__ f, float* __restrict__ ft)
{
    __shared__ float tile[64][65];
    const int b  = blockIdx.x >> 5;
    const int n0 = (blockIdx.x & 31) << 6;
    const int tl = threadIdx.x & 63;
    const int tg = threadIdx.x >> 6;      // 0..3

    for (int c = tg; c < 64; c += 4)
        tile[c][tl] = f[(size_t)(b * 64 + c) * NN + n0 + tl];   // coalesced
    __syncthreads();
    for (int nn2 = tg; nn2 < 64; nn2 += 4)
        ft[((size_t)b * NN + n0 + nn2) * 64 + tl] = tile[tl][nn2]; // coalesced
}

// ---------------------------------------------------------------------------
// KNN: one wave per query. Each lane holds 32 fp64 d2 in REGISTERS
// (m = lane + 64*j, coalesced x loads). 20 rounds of shfl lex-argmin
// (exact fp64 membership, stable lowest-index ties). No LDS, no barriers.
// ---------------------------------------------------------------------------
__global__ __launch_bounds__(64) void knn_kernel(
    const float* __restrict__ x, unsigned short* __restrict__ idx_out)
{
    const int t = threadIdx.x;
    const int p = blockIdx.x;
    const int b = p >> 11;
    const int n = p & (NN - 1);

    const float* xb0 = x + (size_t)(b * 3 + 0) * NN;
    const float* xb1 = x + (size_t)(b * 3 + 1) * NN;
    const float* xb2 = x + (size_t)(b * 3 + 2) * NN;

    const double qx = (double)xb0[n], qy = (double)xb1[n], qz = (double)xb2[n];

    double d2r[32];
#pragma unroll
    for (int j = 0; j < 32; ++j) {
        int m = t + 64 * j;
        double dx = (double)xb0[m] - qx;
        double dy = (double)xb1[m] - qy;
        double dz = (double)xb2[m] - qz;
        d2r[j] = dx * dx + dy * dy + dz * dz;
    }

    // local argmin (ascending j => ascending m => stable lowest-index)
    double lmin = d2r[0]; int lidx = t;
#pragma unroll
    for (int j = 1; j < 32; ++j) {
        if (d2r[j] < lmin) { lmin = d2r[j]; lidx = t + 64 * j; }
    }

    unsigned short* op = idx_out + (size_t)p * KK;
    for (int k = 0; k < KK; ++k) {
        double bd = lmin; int bi = lidx;
#pragma unroll
        for (int off = 32; off > 0; off >>= 1) {
            double od = __shfl_down(bd, off);
            int   oi  = __shfl_down(bi, off);
            if (od < bd || (od == bd && oi < bi)) { bd = od; bi = oi; }
        }
        bi = __shfl(bi, 0);                      // broadcast winner
        if (t == 0) op[k] = (unsigned short)bi;
        if ((bi & 63) == t) {                    // owner lane: kill + rescan
            int jw = bi >> 6;
#pragma unroll
            for (int j = 0; j < 32; ++j)
                if (j == jw) d2r[j] = 1e300;
            lmin = d2r[0]; lidx = t;
#pragma unroll
            for (int j = 1; j < 32; ++j) {
                if (d2r[j] < lmin) { lmin = d2r[j]; lidx = t + 64 * j; }
            }
        }
    }
}

// ---------------------------------------------------------------------------
// Per-point stage, 4 points/block. feats in registers, agg in LDS; conv on
// coalesced wT4 with 4 independent accumulators (chain broken).
// ---------------------------------------------------------------------------
__global__ __launch_bounds__(256, 3) void point_kernel(
    const float* __restrict__ x,
    const float* __restrict__ feature,
    const float* __restrict__ featT,     // may be null
    const float* __restrict__ kern,
    const float* __restrict__ pad,
    const float* __restrict__ mlp_w,
    const float* __restrict__ mlp_b,
    const float4* __restrict__ wT4,
    const float* __restrict__ conv_b,
    const float* __restrict__ mowT,
    const float* __restrict__ mob,
    const unsigned short* __restrict__ idx,
    int use_ft,
    float* __restrict__ out)
{
    __shared__ __align__(16) float agg_s[PPB][C2 * KSS];   // 40960 B
    __shared__ float perm_s[PPB][KK][KSS];                 // 6400 B
    __shared__ float xr_s[PPB][KK][3];
    __shared__ float xd_s[PPB][KK];
    __shared__ float xrep_s[PPB][3];
    __shared__ float colden_s[PPB][KSS];
    __shared__ float fcol_s[PPB][CIN];
    __shared__ int   nid_s[PPB][KK];

    const int tid  = threadIdx.x;
    const int w    = tid >> 6;
    const int lane = tid & 63;
    const int p    = blockIdx.x * PPB + w;
    const int b    = p >> 11;
    const int n    = p & (NN - 1);

    const float* xb0 = x + (size_t)(b * 3 + 0) * NN;
    const float* xb1 = x + (size_t)(b * 3 + 1) * NN;
    const float* xb2 = x + (size_t)(b * 3 + 2) * NN;

    if (lane < KK) nid_s[w][lane] = (int)idx[(size_t)p * KK + lane];
    if (use_ft) fcol_s[w][lane] = featT[((size_t)b * NN + n) * 64 + lane];
    else        fcol_s[w][lane] = feature[(size_t)(b * CIN + lane) * NN + n];
    __syncthreads();

    if (lane == 0) {
        int m0 = nid_s[w][0];
        xrep_s[w][0] = xb0[m0]; xrep_s[w][1] = xb1[m0]; xrep_s[w][2] = xb2[m0];
    }
    __syncthreads();
    if (lane < KK) {
        int m = nid_s[w][lane];
        float rx = xb0[m] - xrep_s[w][0];
        float ry = xb1[m] - xrep_s[w][1];
        float rz = xb2[m] - xrep_s[w][2];
        xr_s[w][lane][0] = rx; xr_s[w][lane][1] = ry; xr_s[w][lane][2] = rz;
        xd_s[w][lane] = sqrtf(rx * rx + ry * ry + rz * rz + 1e-12f);
    }
    __syncthreads();

    // ---- perm: relu -> colnorm -> square -> colnorm -> >0.1 ----
    for (int e = lane; e < KK * KSS; e += 64) {
        int k = e / KSS, m = e % KSS;
        float v = xr_s[w][k][0] * kern[0 * KSS + m]
                + xr_s[w][k][1] * kern[1 * KSS + m]
                + xr_s[w][k][2] * kern[2 * KSS + m]
                + pad[k * KSS + m];
        perm_s[w][k][m] = v > 0.0f ? v : 0.0f;
    }
    __syncthreads();
    if (lane < KSS) {
        float s = 0.0f;
        for (int k = 0; k < KK; ++k) s += perm_s[w][k][lane];
        colden_s[w][lane] = s + 1e-6f;
    }
    __syncthreads();
    for (int e = lane; e < KK * KSS; e += 64) {
        int k = e / KSS, m = e % KSS;
        float v = perm_s[w][k][m] / colden_s[w][m];
        perm_s[w][k][m] = v * v;
    }
    __syncthreads();
    if (lane < KSS) {
        float s = 0.0f;
        for (int k = 0; k < KK; ++k) s += perm_s[w][k][lane];
        colden_s[w][lane] = s + 1e-6f;
    }
    __syncthreads();
    for (int e = lane; e < KK * KSS; e += 64) {
        int k = e / KSS, m = e % KSS;
        float v = perm_s[w][k][m] / colden_s[w][m];
        perm_s[w][k][m] = v > 0.1f ? v : 0.0f;
    }
    __syncthreads();

    // ---- feats in registers ----
    float fg[KK], fm[KK];
    if (use_ft) {
        const float* fp = featT + ((size_t)b * NN) * 64 + lane;
#pragma unroll
        for (int k = 0; k < KK; ++k)
            fg[k] = fp[(size_t)nid_s[w][k] * 64];            // coalesced per k
    } else {
#pragma unroll
        for (int k = 0; k < KK; ++k)
            fg[k] = feature[(size_t)(b * CIN + lane) * NN + nid_s[w][k]];
    }
    {
        float w0 = mlp_w[lane * 7 + 0], w1 = mlp_w[lane * 7 + 1];
        float w2 = mlp_w[lane * 7 + 2], w3 = mlp_w[lane * 7 + 3];
        float w4 = mlp_w[lane * 7 + 4], w5 = mlp_w[lane * 7 + 5];
        float w6 = mlp_w[lane * 7 + 6];
        float bias = mlp_b[lane];
#pragma unroll
        for (int k = 0; k < KK; ++k) {
            fm[k] = xrep_s[w][0] * w0 + xrep_s[w][1] * w1 + xrep_s[w][2] * w2
                  + xr_s[w][k][0] * w3 + xr_s[w][k][1] * w4 + xr_s[w][k][2] * w5
                  + xd_s[w][k] * w6 + bias;
        }
    }

    // ---- agg rows c=lane, c=64+lane (k ascending) ----
#pragma unroll
    for (int m = 0; m < KSS; ++m) {
        float s = 0.0f, s2 = 0.0f;
#pragma unroll
        for (int k = 0; k < KK; ++k) {
            float pv = perm_s[w][k][m];
            s  += fg[k] * pv;
            s2 += fm[k] * pv;
        }
        agg_s[w][lane * KSS + m]         = s;
        agg_s[w][(CIN + lane) * KSS + m] = s2;
    }
    __syncthreads();

    // ---- conv: 4 independent accumulators + residual ----
    {
        float a0 = 0.0f, a1 = 0.0f, a2 = 0.0f, a3 = 0.0f;
        const float4* wp = wT4 + lane;
#pragma unroll 4
        for (int j4 = 0; j4 < NJ4; ++j4) {
            float4 wv = wp[(size_t)j4 * 64];                   // 1 KB coalesced
            float4 a  = *(const float4*)(&agg_s[w][j4 * 4]);   // LDS broadcast
            a0 += wv.x * a.x;
            a1 += wv.y * a.y;
            a2 += wv.z * a.z;
            a3 += wv.w * a.w;
        }
        float acc = conv_b[lane] + ((a0 + a1) + (a2 + a3));
        for (int c = 0; c < CIN; ++c)
            acc += fcol_s[w][c] * mowT[c * COUT + lane];       // coalesced
        acc += mob[lane];
        out[(size_t)(b * COUT + lane) * NN + n] = acc;
    }
}

// ---------------------------------------------------------------------------
// BatchNorm per channel over (B,N), fp32 in-place. 64 blocks x 256.
// ---------------------------------------------------------------------------
__global__ __launch_bounds__(256) void bn_kernel(
    float* __restrict__ out,
    const float* __restrict__ gamma,
    const float* __restrict__ beta)
{
    const int o = blockIdx.x;
    __shared__ float s1[256], s2[256];
    __shared__ float mean_s, inv_s;

    float a = 0.0f, q = 0.0f;
    for (int i = threadIdx.x; i < BB * NN; i += 256) {
        int b = i >> 11, n = i & (NN - 1);
        float v = out[(size_t)(b * COUT + o) * NN + n];
        a += v; q += v * v;
    }
    s1[threadIdx.x] = a; s2[threadIdx.x] = q;
    __syncthreads();
    for (int s = 128; s > 0; s >>= 1) {
        if (threadIdx.x < s) {
            s1[threadIdx.x] += s1[threadIdx.x + s];
            s2[threadIdx.x] += s2[threadIdx.x + s];
        }
        __syncthreads();
    }
    if (threadIdx.x == 0) {
        const float M = (float)(BB * NN);
        float mean = s1[0] / M;
        float var  = s2[0] / M - mean * mean;
        if (var < 0.0f) var = 0.0f;
        mean_s = mean;
        inv_s  = 1.0f / sqrtf(var + 1e-5f);
    }
    __syncthreads();
    const float mean = mean_s, inv = inv_s;
    const float g = gamma[o], be = beta[o];
    for (int i = threadIdx.x; i < BB * NN; i += 256) {
        int b = i >> 11, n = i & (NN - 1);
        size_t ad = (size_t)(b * COUT + o) * NN + n;
        out[ad] = (out[ad] - mean) * inv * g + be;
    }
}

// ---------------------------------------------------------------------------
extern "C" void kernel_launch(void* const* d_in, const int* in_sizes, int n_in,
                              void* d_out, int out_size, void* d_ws, size_t ws_size,
                              hipStream_t stream)
{
    const float* x       = (const float*)d_in[0];
    const float* feature = (const float*)d_in[1];
    const float* kern    = (const float*)d_in[2];
    const float* pad     = (const float*)d_in[3];
    const float* mlp_w   = (const float*)d_in[4];
    const float* mlp_b   = (const float*)d_in[5];
    const float* conv_w  = (const float*)d_in[6];
    const float* conv_b  = (const float*)d_in[7];
    const float* mow     = (const float*)d_in[8];
    const float* mob     = (const float*)d_in[9];
    const float* gamma   = (const float*)d_in[10];
    const float* beta    = (const float*)d_in[11];

    char* wsp = (char*)d_ws;
    float4*         wT4     = (float4*)wsp;                        // 655360 B
    unsigned short* idx_buf = (unsigned short*)(wsp + 655360);     // 655360 B
    float*          mowT    = (float*)(wsp + 655360 * 2);          //  16384 B
    float*          featT   = (float*)(wsp + 655360 * 2 + 16384);  // 4 MiB
    const size_t    need_ft = (size_t)655360 * 2 + 16384 + (size_t)BB * NN * CIN * 4;
    const int       use_ft  = (ws_size >= need_ft) ? 1 : 0;

    float* out = (float*)d_out;

    prep_kernel<<<(NJ4 * COUT + 255) / 256, 256, 0, stream>>>(conv_w, mow, wT4, mowT);
    if (use_ft)
        transpose_kernel<<<BB * 32, 256, 0, stream>>>(feature, featT);
    knn_kernel<<<BB * NN, 64, 0, stream>>>(x, idx_buf);
    point_kernel<<<BB * NN / PPB, 256, 0, stream>>>(x, feature, featT, kern, pad,
                                                    mlp_w, mlp_b, wT4, conv_b,
                                                    mowT, mob, idx_buf, use_ft, out);
    bn_kernel<<<COUT, 256, 0, stream>>>(out, gamma, beta);
}

// Round 19
// 532.567 us; speedup vs baseline: 4.3298x; 1.2551x over previous
//
#include <hip/hip_runtime.h>
#include <cstddef>

#define BB   8
#define NN   2048
#define CIN  64
#define COUT 64
#define KK   20
#define KSS  20
#define C2   128   // 2*CIN
#define NJ4  (C2 * KSS / 4)   // 640 float4 rows of the conv matrix
#define PPB  4                 // points per block (point_kernel)
#define JQ   (NJ4 / PPB)       // 160 j4-rows per wave in cooperative conv

// ---------------------------------------------------------------------------
// Prep: wT4[j4*64 + t] = conv_w[t][4*j4..+3]; mowT[c*64 + o] = mow[o][c]
// ---------------------------------------------------------------------------
__global__ __launch_bounds__(256) void prep_kernel(
    const float* __restrict__ cw, const float* __restrict__ mw,
    float4* __restrict__ wT4, float* __restrict__ mowT)
{
    int i = blockIdx.x * 256 + threadIdx.x;
    if (i < NJ4 * COUT) {
        int j4 = i >> 6, t = i & 63;
        const float* s = cw + (size_t)t * (C2 * KSS) + j4 * 4;
        wT4[i] = make_float4(s[0], s[1], s[2], s[3]);
    }
    if (i < COUT * CIN) {
        int o = i >> 6, c = i & 63;
        mowT[c * COUT + o] = mw[o * CIN + c];
    }
}

// ---------------------------------------------------------------------------
// KNN: one wave per query. 32 fp64 d2 per lane in registers, 20 rounds of
// shfl lex-argmin (exact fp64 membership, stable lowest-index ties).
// ---------------------------------------------------------------------------
__global__ __launch_bounds__(64) void knn_kernel(
    const float* __restrict__ x, unsigned short* __restrict__ idx_out)
{
    const int t = threadIdx.x;
    const int p = blockIdx.x;
    const int b = p >> 11;
    const int n = p & (NN - 1);

    const float* xb0 = x + (size_t)(b * 3 + 0) * NN;
    const float* xb1 = x + (size_t)(b * 3 + 1) * NN;
    const float* xb2 = x + (size_t)(b * 3 + 2) * NN;

    const double qx = (double)xb0[n], qy = (double)xb1[n], qz = (double)xb2[n];

    double d2r[32];
#pragma unroll
    for (int j = 0; j < 32; ++j) {
        int m = t + 64 * j;
        double dx = (double)xb0[m] - qx;
        double dy = (double)xb1[m] - qy;
        double dz = (double)xb2[m] - qz;
        d2r[j] = dx * dx + dy * dy + dz * dz;
    }

    double lmin = d2r[0]; int lidx = t;
#pragma unroll
    for (int j = 1; j < 32; ++j) {
        if (d2r[j] < lmin) { lmin = d2r[j]; lidx = t + 64 * j; }
    }

    unsigned short* op = idx_out + (size_t)p * KK;
    for (int k = 0; k < KK; ++k) {
        double bd = lmin; int bi = lidx;
#pragma unroll
        for (int off = 32; off > 0; off >>= 1) {
            double od = __shfl_down(bd, off);
            int   oi  = __shfl_down(bi, off);
            if (od < bd || (od == bd && oi < bi)) { bd = od; bi = oi; }
        }
        bi = __shfl(bi, 0);
        if (t == 0) op[k] = (unsigned short)bi;
        if ((bi & 63) == t) {
            int jw = bi >> 6;
#pragma unroll
            for (int j = 0; j < 32; ++j)
                if (j == jw) d2r[j] = 1e300;
            lmin = d2r[0]; lidx = t;
#pragma unroll
            for (int j = 1; j < 32; ++j) {
                if (d2r[j] < lmin) { lmin = d2r[j]; lidx = t + 64 * j; }
            }
        }
    }
}

// ---------------------------------------------------------------------------
// Per-point stage, 4 points/block. agg in LDS; conv COOPERATIVE across the
// 4 waves: wave w covers j4 in [w*JQ,(w+1)*JQ) for all 4 points (each wT4
// load reused 4x), then 4 KB LDS cross-wave reduction.
// ---------------------------------------------------------------------------
__global__ __launch_bounds__(256, 3) void point_kernel(
    const float* __restrict__ x,
    const float* __restrict__ feature,
    const float* __restrict__ kern,
    const float* __restrict__ pad,
    const float* __restrict__ mlp_w,
    const float* __restrict__ mlp_b,
    const float4* __restrict__ wT4,
    const float* __restrict__ conv_b,
    const float* __restrict__ mowT,
    const float* __restrict__ mob,
    const unsigned short* __restrict__ idx,
    float* __restrict__ out)
{
    __shared__ __align__(16) float agg_s[PPB][C2 * KSS];   // 40960 B
    __shared__ float perm_s[PPB][KK][KSS];                 // 6400 B
    __shared__ float red_s[PPB][PPB][64];                  // 4096 B
    __shared__ float xr_s[PPB][KK][3];
    __shared__ float xd_s[PPB][KK];
    __shared__ float xrep_s[PPB][3];
    __shared__ float colden_s[PPB][KSS];
    __shared__ float fcol_s[PPB][CIN];
    __shared__ int   nid_s[PPB][KK];

    const int tid  = threadIdx.x;
    const int w    = tid >> 6;
    const int lane = tid & 63;
    const int p    = blockIdx.x * PPB + w;
    const int b    = p >> 11;
    const int n    = p & (NN - 1);

    const float* xb0 = x + (size_t)(b * 3 + 0) * NN;
    const float* xb1 = x + (size_t)(b * 3 + 1) * NN;
    const float* xb2 = x + (size_t)(b * 3 + 2) * NN;

    if (lane < KK) nid_s[w][lane] = (int)idx[(size_t)p * KK + lane];
    fcol_s[w][lane] = feature[(size_t)(b * CIN + lane) * NN + n];
    __syncthreads();

    if (lane == 0) {
        int m0 = nid_s[w][0];
        xrep_s[w][0] = xb0[m0]; xrep_s[w][1] = xb1[m0]; xrep_s[w][2] = xb2[m0];
    }
    __syncthreads();
    if (lane < KK) {
        int m = nid_s[w][lane];
        float rx = xb0[m] - xrep_s[w][0];
        float ry = xb1[m] - xrep_s[w][1];
        float rz = xb2[m] - xrep_s[w][2];
        xr_s[w][lane][0] = rx; xr_s[w][lane][1] = ry; xr_s[w][lane][2] = rz;
        xd_s[w][lane] = sqrtf(rx * rx + ry * ry + rz * rz + 1e-12f);
    }
    __syncthreads();

    // ---- perm: relu -> colnorm -> square -> colnorm -> >0.1 ----
    for (int e = lane; e < KK * KSS; e += 64) {
        int k = e / KSS, m = e % KSS;
        float v = xr_s[w][k][0] * kern[0 * KSS + m]
                + xr_s[w][k][1] * kern[1 * KSS + m]
                + xr_s[w][k][2] * kern[2 * KSS + m]
                + pad[k * KSS + m];
        perm_s[w][k][m] = v > 0.0f ? v : 0.0f;
    }
    __syncthreads();
    if (lane < KSS) {
        float s = 0.0f;
        for (int k = 0; k < KK; ++k) s += perm_s[w][k][lane];
        colden_s[w][lane] = s + 1e-6f;
    }
    __syncthreads();
    for (int e = lane; e < KK * KSS; e += 64) {
        int k = e / KSS, m = e % KSS;
        float v = perm_s[w][k][m] / colden_s[w][m];
        perm_s[w][k][m] = v * v;
    }
    __syncthreads();
    if (lane < KSS) {
        float s = 0.0f;
        for (int k = 0; k < KK; ++k) s += perm_s[w][k][lane];
        colden_s[w][lane] = s + 1e-6f;
    }
    __syncthreads();
    for (int e = lane; e < KK * KSS; e += 64) {
        int k = e / KSS, m = e % KSS;
        float v = perm_s[w][k][m] / colden_s[w][m];
        perm_s[w][k][m] = v > 0.1f ? v : 0.0f;
    }
    __syncthreads();

    // ---- feats in registers (direct gather; featT path reverted) ----
    float fg[KK], fm[KK];
#pragma unroll
    for (int k = 0; k < KK; ++k)
        fg[k] = feature[(size_t)(b * CIN + lane) * NN + nid_s[w][k]];
    {
        float w0 = mlp_w[lane * 7 + 0], w1 = mlp_w[lane * 7 + 1];
        float w2 = mlp_w[lane * 7 + 2], w3 = mlp_w[lane * 7 + 3];
        float w4 = mlp_w[lane * 7 + 4], w5 = mlp_w[lane * 7 + 5];
        float w6 = mlp_w[lane * 7 + 6];
        float bias = mlp_b[lane];
#pragma unroll
        for (int k = 0; k < KK; ++k) {
            fm[k] = xrep_s[w][0] * w0 + xrep_s[w][1] * w1 + xrep_s[w][2] * w2
                  + xr_s[w][k][0] * w3 + xr_s[w][k][1] * w4 + xr_s[w][k][2] * w5
                  + xd_s[w][k] * w6 + bias;
        }
    }

    // ---- agg rows c=lane, c=64+lane ----
#pragma unroll
    for (int m = 0; m < KSS; ++m) {
        float s = 0.0f, s2 = 0.0f;
#pragma unroll
        for (int k = 0; k < KK; ++k) {
            float pv = perm_s[w][k][m];
            s  += fg[k] * pv;
            s2 += fm[k] * pv;
        }
        agg_s[w][lane * KSS + m]         = s;
        agg_s[w][(CIN + lane) * KSS + m] = s2;
    }
    __syncthreads();

    // ---- cooperative conv: wave w -> j4 in [w*JQ,(w+1)*JQ) for ALL points --
    {
        float pa0 = 0.0f, pa1 = 0.0f, pa2 = 0.0f, pa3 = 0.0f;
        const float4* wp = wT4 + lane;
        const int j4lo = w * JQ, j4hi = j4lo + JQ;
#pragma unroll 2
        for (int j4 = j4lo; j4 < j4hi; ++j4) {
            float4 wv = wp[(size_t)j4 * 64];                   // 1 KB coalesced
            float4 a0 = *(const float4*)(&agg_s[0][j4 * 4]);
            float4 a1 = *(const float4*)(&agg_s[1][j4 * 4]);
            float4 a2 = *(const float4*)(&agg_s[2][j4 * 4]);
            float4 a3 = *(const float4*)(&agg_s[3][j4 * 4]);
            pa0 += wv.x * a0.x; pa0 += wv.y * a0.y; pa0 += wv.z * a0.z; pa0 += wv.w * a0.w;
            pa1 += wv.x * a1.x; pa1 += wv.y * a1.y; pa1 += wv.z * a1.z; pa1 += wv.w * a1.w;
            pa2 += wv.x * a2.x; pa2 += wv.y * a2.y; pa2 += wv.z * a2.z; pa2 += wv.w * a2.w;
            pa3 += wv.x * a3.x; pa3 += wv.y * a3.y; pa3 += wv.z * a3.z; pa3 += wv.w * a3.w;
        }
        red_s[0][w][lane] = pa0;
        red_s[1][w][lane] = pa1;
        red_s[2][w][lane] = pa2;
        red_s[3][w][lane] = pa3;
    }
    __syncthreads();

    // ---- wave w finalizes point w: reduce quarters + residual + biases ----
    {
        float acc = conv_b[lane]
                  + ((red_s[w][0][lane] + red_s[w][1][lane])
                   + (red_s[w][2][lane] + red_s[w][3][lane]));
        for (int c = 0; c < CIN; ++c)
            acc += fcol_s[w][c] * mowT[c * COUT + lane];       // coalesced
        acc += mob[lane];
        out[(size_t)(b * COUT + lane) * NN + n] = acc;
    }
}

// ---------------------------------------------------------------------------
// BatchNorm per channel over (B,N), fp32 in-place. 64 blocks x 256.
// ---------------------------------------------------------------------------
__global__ __launch_bounds__(256) void bn_kernel(
    float* __restrict__ out,
    const float* __restrict__ gamma,
    const float* __restrict__ beta)
{
    const int o = blockIdx.x;
    __shared__ float s1[256], s2[256];
    __shared__ float mean_s, inv_s;

    float a = 0.0f, q = 0.0f;
    for (int i = threadIdx.x; i < BB * NN; i += 256) {
        int b = i >> 11, n = i & (NN - 1);
        float v = out[(size_t)(b * COUT + o) * NN + n];
        a += v; q += v * v;
    }
    s1[threadIdx.x] = a; s2[threadIdx.x] = q;
    __syncthreads();
    for (int s = 128; s > 0; s >>= 1) {
        if (threadIdx.x < s) {
            s1[threadIdx.x] += s1[threadIdx.x + s];
            s2[threadIdx.x] += s2[threadIdx.x + s];
        }
        __syncthreads();
    }
    if (threadIdx.x == 0) {
        const float M = (float)(BB * NN);
        float mean = s1[0] / M;
        float var  = s2[0] / M - mean * mean;
        if (var < 0.0f) var = 0.0f;
        mean_s = mean;
        inv_s  = 1.0f / sqrtf(var + 1e-5f);
    }
    __syncthreads();
    const float mean = mean_s, inv = inv_s;
    const float g = gamma[o], be = beta[o];
    for (int i = threadIdx.x; i < BB * NN; i += 256) {
        int b = i >> 11, n = i & (NN - 1);
        size_t ad = (size_t)(b * COUT + o) * NN + n;
        out[ad] = (out[ad] - mean) * inv * g + be;
    }
}

// ---------------------------------------------------------------------------
extern "C" void kernel_launch(void* const* d_in, const int* in_sizes, int n_in,
                              void* d_out, int out_size, void* d_ws, size_t ws_size,
                              hipStream_t stream)
{
    const float* x       = (const float*)d_in[0];
    const float* feature = (const float*)d_in[1];
    const float* kern    = (const float*)d_in[2];
    const float* pad     = (const float*)d_in[3];
    const float* mlp_w   = (const float*)d_in[4];
    const float* mlp_b   = (const float*)d_in[5];
    const float* conv_w  = (const float*)d_in[6];
    const float* conv_b  = (const float*)d_in[7];
    const float* mow     = (const float*)d_in[8];
    const float* mob     = (const float*)d_in[9];
    const float* gamma   = (const float*)d_in[10];
    const float* beta    = (const float*)d_in[11];

    char* wsp = (char*)d_ws;
    float4*         wT4     = (float4*)wsp;                        // 655360 B
    unsigned short* idx_buf = (unsigned short*)(wsp + 655360);     // 655360 B
    float*          mowT    = (float*)(wsp + 655360 * 2);          //  16384 B

    float* out = (float*)d_out;

    prep_kernel<<<(NJ4 * COUT + 255) / 256, 256, 0, stream>>>(conv_w, mow, wT4, mowT);
    knn_kernel<<<BB * NN, 64, 0, stream>>>(x, idx_buf);
    point_kernel<<<BB * NN / PPB, 256, 0, stream>>>(x, feature, kern, pad,
                                                    mlp_w, mlp_b, wT4, conv_b,
                                                    mowT, mob, idx_buf, out);
    bn_kernel<<<COUT, 256, 0, stream>>>(out, gamma, beta);
}

// Round 20
// 514.075 us; speedup vs baseline: 4.4855x; 1.0360x over previous
//
#include <hip/hip_runtime.h>
#include <cstddef>

#define BB   8
#define NN   2048
#define CIN  64
#define COUT 64
#define KK   20
#define KSS  20
#define C2   128   // 2*CIN
#define NJ4  (C2 * KSS / 4)   // 640 float4 rows of the conv matrix
#define PPB  4                 // points per block (point_kernel)
#define JQ   (NJ4 / PPB)       // 160 j4-rows per wave in cooperative conv
#define NC   24                // fp32 candidate count for knn refine

// ---------------------------------------------------------------------------
// Prep: wT4[j4*64 + t] = conv_w[t][4*j4..+3]; mowT[c*64 + o] = mow[o][c]
// ---------------------------------------------------------------------------
__global__ __launch_bounds__(256) void prep_kernel(
    const float* __restrict__ cw, const float* __restrict__ mw,
    float4* __restrict__ wT4, float* __restrict__ mowT)
{
    int i = blockIdx.x * 256 + threadIdx.x;
    if (i < NJ4 * COUT) {
        int j4 = i >> 6, t = i & 63;
        const float* s = cw + (size_t)t * (C2 * KSS) + j4 * 4;
        wT4[i] = make_float4(s[0], s[1], s[2], s[3]);
    }
    if (i < COUT * CIN) {
        int o = i >> 6, c = i & 63;
        mowT[c * COUT + o] = mw[o * CIN + c];
    }
}

// ---------------------------------------------------------------------------
// KNN: fp32 candidate selection (top-2 cache + killmask, 24 rounds) then
// fp64 exact re-ranking of the 24 candidates -> top-20 membership is
// fp64-exact, ties lexicographic (d, index). One wave per query.
// ---------------------------------------------------------------------------
__global__ __launch_bounds__(64) void knn_kernel(
    const float* __restrict__ x, unsigned short* __restrict__ idx_out)
{
    const int t = threadIdx.x;
    const int p = blockIdx.x;
    const int b = p >> 11;
    const int n = p & (NN - 1);

    const float* xb0 = x + (size_t)(b * 3 + 0) * NN;
    const float* xb1 = x + (size_t)(b * 3 + 1) * NN;
    const float* xb2 = x + (size_t)(b * 3 + 2) * NN;

    const float qx = xb0[n], qy = xb1[n], qz = xb2[n];

    float d2r[32];
#pragma unroll
    for (int j = 0; j < 32; ++j) {
        int m = t + 64 * j;
        float dx = xb0[m] - qx;
        float dy = xb1[m] - qy;
        float dz = xb2[m] - qz;
        d2r[j] = dx * dx + dy * dy + dz * dz;
    }

    // per-lane top-2 (ascending j + strict < => stable lowest-index)
    const float FINF = __int_as_float(0x7f800000);
    float m1 = FINF, m2 = FINF; int i1 = 0x7fffffff, i2 = 0x7fffffff;
#pragma unroll
    for (int j = 0; j < 32; ++j) {
        float v = d2r[j]; int id = t + 64 * j;
        if (v < m1)      { m2 = m1; i2 = i1; m1 = v; i1 = id; }
        else if (v < m2) { m2 = v; i2 = id; }
    }

    unsigned killmask = 0u;
    int myci = 0x7fffffff;          // this lane's refine candidate

    for (int k = 0; k < NC; ++k) {
        float bd = m1; int bi = i1;
#pragma unroll
        for (int off = 32; off > 0; off >>= 1) {
            float od = __shfl_down(bd, off);
            int   oi = __shfl_down(bi, off);
            if (od < bd || (od == bd && oi < bi)) { bd = od; bi = oi; }
        }
        bi = __shfl(bi, 0);
        if (t == k) myci = bi;                     // lane k owns candidate k
        if ((bi & 63) == t) {                      // owner lane: consume
            killmask |= 1u << (bi >> 6);
            if (m2 < FINF) { m1 = m2; i1 = i2; m2 = FINF; i2 = 0x7fffffff; }
            else {
                m1 = FINF; i1 = 0x7fffffff; m2 = FINF; i2 = 0x7fffffff;
#pragma unroll
                for (int j = 0; j < 32; ++j) {
                    if (!(killmask & (1u << j))) {
                        float v = d2r[j]; int id = t + 64 * j;
                        if (v < m1)      { m2 = m1; i2 = i1; m1 = v; i1 = id; }
                        else if (v < m2) { m2 = v; i2 = id; }
                    }
                }
            }
        }
    }

    // fp64 exact re-rank of the 24 candidates
    double dd = 1e300;
    if (t < NC) {
        int m = myci;
        double dx = (double)xb0[m] - (double)qx;
        double dy = (double)xb1[m] - (double)qy;
        double dz = (double)xb2[m] - (double)qz;
        dd = dx * dx + dy * dy + dz * dz;
    }
    unsigned short* op = idx_out + (size_t)p * KK;
    for (int k = 0; k < KK; ++k) {
        double bd = dd; int bi = myci;
#pragma unroll
        for (int off = 32; off > 0; off >>= 1) {
            double od = __shfl_down(bd, off);
            int   oi  = __shfl_down(bi, off);
            if (od < bd || (od == bd && oi < bi)) { bd = od; bi = oi; }
        }
        bi = __shfl(bi, 0);
        if (t == 0) op[k] = (unsigned short)bi;
        if (myci == bi) dd = 1e300;                // kill taken candidate
    }
}

// ---------------------------------------------------------------------------
// Per-point stage, 4 points/block. agg in LDS; conv cooperative across the
// 4 waves; red_s UNIONED onto perm_s storage (perm dead after agg phase)
// to keep LDS <= 53.3 KB -> 3 blocks/CU.
// ---------------------------------------------------------------------------
__global__ __launch_bounds__(256, 3) void point_kernel(
    const float* __restrict__ x,
    const float* __restrict__ feature,
    const float* __restrict__ kern,
    const float* __restrict__ pad,
    const float* __restrict__ mlp_w,
    const float* __restrict__ mlp_b,
    const float4* __restrict__ wT4,
    const float* __restrict__ conv_b,
    const float* __restrict__ mowT,
    const float* __restrict__ mob,
    const unsigned short* __restrict__ idx,
    float* __restrict__ out)
{
    __shared__ __align__(16) float agg_s[PPB][C2 * KSS];   // 40960 B
    __shared__ __align__(16) float u_s[PPB * KK * KSS];    // 6400 B (perm|red)
    __shared__ float xr_s[PPB][KK][3];
    __shared__ float xd_s[PPB][KK];
    __shared__ float xrep_s[PPB][3];
    __shared__ float colden_s[PPB][KSS];
    __shared__ float fcol_s[PPB][CIN];
    __shared__ int   nid_s[PPB][KK];

    float (*perm_s)[KK][KSS] = (float (*)[KK][KSS])u_s;
    float (*red_s)[PPB][64]  = (float (*)[PPB][64])u_s;

    const int tid  = threadIdx.x;
    const int w    = tid >> 6;
    const int lane = tid & 63;
    const int p    = blockIdx.x * PPB + w;
    const int b    = p >> 11;
    const int n    = p & (NN - 1);

    const float* xb0 = x + (size_t)(b * 3 + 0) * NN;
    const float* xb1 = x + (size_t)(b * 3 + 1) * NN;
    const float* xb2 = x + (size_t)(b * 3 + 2) * NN;

    if (lane < KK) nid_s[w][lane] = (int)idx[(size_t)p * KK + lane];
    fcol_s[w][lane] = feature[(size_t)(b * CIN + lane) * NN + n];
    __syncthreads();

    if (lane == 0) {
        int m0 = nid_s[w][0];
        xrep_s[w][0] = xb0[m0]; xrep_s[w][1] = xb1[m0]; xrep_s[w][2] = xb2[m0];
    }
    __syncthreads();
    if (lane < KK) {
        int m = nid_s[w][lane];
        float rx = xb0[m] - xrep_s[w][0];
        float ry = xb1[m] - xrep_s[w][1];
        float rz = xb2[m] - xrep_s[w][2];
        xr_s[w][lane][0] = rx; xr_s[w][lane][1] = ry; xr_s[w][lane][2] = rz;
        xd_s[w][lane] = sqrtf(rx * rx + ry * ry + rz * rz + 1e-12f);
    }
    __syncthreads();

    // ---- perm: relu -> colnorm -> square -> colnorm -> >0.1 ----
    for (int e = lane; e < KK * KSS; e += 64) {
        int k = e / KSS, m = e % KSS;
        float v = xr_s[w][k][0] * kern[0 * KSS + m]
                + xr_s[w][k][1] * kern[1 * KSS + m]
                + xr_s[w][k][2] * kern[2 * KSS + m]
                + pad[k * KSS + m];
        perm_s[w][k][m] = v > 0.0f ? v : 0.0f;
    }
    __syncthreads();
    if (lane < KSS) {
        float s = 0.0f;
        for (int k = 0; k < KK; ++k) s += perm_s[w][k][lane];
        colden_s[w][lane] = s + 1e-6f;
    }
    __syncthreads();
    for (int e = lane; e < KK * KSS; e += 64) {
        int k = e / KSS, m = e % KSS;
        float v = perm_s[w][k][m] / colden_s[w][m];
        perm_s[w][k][m] = v * v;
    }
    __syncthreads();
    if (lane < KSS) {
        float s = 0.0f;
        for (int k = 0; k < KK; ++k) s += perm_s[w][k][lane];
        colden_s[w][lane] = s + 1e-6f;
    }
    __syncthreads();
    for (int e = lane; e < KK * KSS; e += 64) {
        int k = e / KSS, m = e % KSS;
        float v = perm_s[w][k][m] / colden_s[w][m];
        perm_s[w][k][m] = v > 0.1f ? v : 0.0f;
    }
    __syncthreads();

    // ---- feats in registers ----
    float fg[KK], fm[KK];
#pragma unroll
    for (int k = 0; k < KK; ++k)
        fg[k] = feature[(size_t)(b * CIN + lane) * NN + nid_s[w][k]];
    {
        float w0 = mlp_w[lane * 7 + 0], w1 = mlp_w[lane * 7 + 1];
        float w2 = mlp_w[lane * 7 + 2], w3 = mlp_w[lane * 7 + 3];
        float w4 = mlp_w[lane * 7 + 4], w5 = mlp_w[lane * 7 + 5];
        float w6 = mlp_w[lane * 7 + 6];
        float bias = mlp_b[lane];
#pragma unroll
        for (int k = 0; k < KK; ++k) {
            fm[k] = xrep_s[w][0] * w0 + xrep_s[w][1] * w1 + xrep_s[w][2] * w2
                  + xr_s[w][k][0] * w3 + xr_s[w][k][1] * w4 + xr_s[w][k][2] * w5
                  + xd_s[w][k] * w6 + bias;
        }
    }

    // ---- agg rows c=lane, c=64+lane (perm's LAST use) ----
#pragma unroll
    for (int m = 0; m < KSS; ++m) {
        float s = 0.0f, s2 = 0.0f;
#pragma unroll
        for (int k = 0; k < KK; ++k) {
            float pv = perm_s[w][k][m];
            s  += fg[k] * pv;
            s2 += fm[k] * pv;
        }
        agg_s[w][lane * KSS + m]         = s;
        agg_s[w][(CIN + lane) * KSS + m] = s2;
    }
    __syncthreads();   // after this barrier perm_s is dead; red_s takes over

    // ---- cooperative conv: wave w -> j4 in [w*JQ,(w+1)*JQ) for ALL points --
    {
        float pa0 = 0.0f, pa1 = 0.0f, pa2 = 0.0f, pa3 = 0.0f;
        const float4* wp = wT4 + lane;
        const int j4lo = w * JQ, j4hi = j4lo + JQ;
#pragma unroll 2
        for (int j4 = j4lo; j4 < j4hi; ++j4) {
            float4 wv = wp[(size_t)j4 * 64];                   // 1 KB coalesced
            float4 a0 = *(const float4*)(&agg_s[0][j4 * 4]);
            float4 a1 = *(const float4*)(&agg_s[1][j4 * 4]);
            float4 a2 = *(const float4*)(&agg_s[2][j4 * 4]);
            float4 a3 = *(const float4*)(&agg_s[3][j4 * 4]);
            pa0 += wv.x * a0.x; pa0 += wv.y * a0.y; pa0 += wv.z * a0.z; pa0 += wv.w * a0.w;
            pa1 += wv.x * a1.x; pa1 += wv.y * a1.y; pa1 += wv.z * a1.z; pa1 += wv.w * a1.w;
            pa2 += wv.x * a2.x; pa2 += wv.y * a2.y; pa2 += wv.z * a2.z; pa2 += wv.w * a2.w;
            pa3 += wv.x * a3.x; pa3 += wv.y * a3.y; pa3 += wv.z * a3.z; pa3 += wv.w * a3.w;
        }
        red_s[0][w][lane] = pa0;
        red_s[1][w][lane] = pa1;
        red_s[2][w][lane] = pa2;
        red_s[3][w][lane] = pa3;
    }
    __syncthreads();

    // ---- wave w finalizes point w ----
    {
        float acc = conv_b[lane]
                  + ((red_s[w][0][lane] + red_s[w][1][lane])
                   + (red_s[w][2][lane] + red_s[w][3][lane]));
        for (int c = 0; c < CIN; ++c)
            acc += fcol_s[w][c] * mowT[c * COUT + lane];
        acc += mob[lane];
        out[(size_t)(b * COUT + lane) * NN + n] = acc;
    }
}

// ---------------------------------------------------------------------------
// BatchNorm per channel over (B,N), fp32 in-place. 64 blocks x 256.
// ---------------------------------------------------------------------------
__global__ __launch_bounds__(256) void bn_kernel(
    float* __restrict__ out,
    const float* __restrict__ gamma,
    const float* __restrict__ beta)
{
    const int o = blockIdx.x;
    __shared__ float s1[256], s2[256];
    __shared__ float mean_s, inv_s;

    float a = 0.0f, q = 0.0f;
    for (int i = threadIdx.x; i < BB * NN; i += 256) {
        int b = i >> 11, n = i & (NN - 1);
        float v = out[(size_t)(b * COUT + o) * NN + n];
        a += v; q += v * v;
    }
    s1[threadIdx.x] = a; s2[threadIdx.x] = q;
    __syncthreads();
    for (int s = 128; s > 0; s >>= 1) {
        if (threadIdx.x < s) {
            s1[threadIdx.x] += s1[threadIdx.x + s];
            s2[threadIdx.x] += s2[threadIdx.x + s];
        }
        __syncthreads();
    }
    if (threadIdx.x == 0) {
        const float M = (float)(BB * NN);
        float mean = s1[0] / M;
        float var  = s2[0] / M - mean * mean;
        if (var < 0.0f) var = 0.0f;
        mean_s = mean;
        inv_s  = 1.0f / sqrtf(var + 1e-5f);
    }
    __syncthreads();
    const float mean = mean_s, inv = inv_s;
    const float g = gamma[o], be = beta[o];
    for (int i = threadIdx.x; i < BB * NN; i += 256) {
        int b = i >> 11, n = i & (NN - 1);
        size_t ad = (size_t)(b * COUT + o) * NN + n;
        out[ad] = (out[ad] - mean) * inv * g + be;
    }
}

// ---------------------------------------------------------------------------
extern "C" void kernel_launch(void* const* d_in, const int* in_sizes, int n_in,
                              void* d_out, int out_size, void* d_ws, size_t ws_size,
                              hipStream_t stream)
{
    const float* x       = (const float*)d_in[0];
    const float* feature = (const float*)d_in[1];
    const float* kern    = (const float*)d_in[2];
    const float* pad     = (const float*)d_in[3];
    const float* mlp_w   = (const float*)d_in[4];
    const float* mlp_b   = (const float*)d_in[5];
    const float* conv_w  = (const float*)d_in[6];
    const float* conv_b  = (const float*)d_in[7];
    const float* mow     = (const float*)d_in[8];
    const float* mob     = (const float*)d_in[9];
    const float* gamma   = (const float*)d_in[10];
    const float* beta    = (const float*)d_in[11];

    char* wsp = (char*)d_ws;
    float4*         wT4     = (float4*)wsp;                        // 655360 B
    unsigned short* idx_buf = (unsigned short*)(wsp + 655360);     // 655360 B
    float*          mowT    = (float*)(wsp + 655360 * 2);          //  16384 B

    float* out = (float*)d_out;

    prep_kernel<<<(NJ4 * COUT + 255) / 256, 256, 0, stream>>>(conv_w, mow, wT4, mowT);
    knn_kernel<<<BB * NN, 64, 0, stream>>>(x, idx_buf);
    point_kernel<<<BB * NN / PPB, 256, 0, stream>>>(x, feature, kern, pad,
                                                    mlp_w, mlp_b, wT4, conv_b,
                                                    mowT, mob, idx_buf, out);
    bn_kernel<<<COUT, 256, 0, stream>>>(out, gamma, beta);
}

// Round 21
// 415.371 us; speedup vs baseline: 5.5514x; 1.2376x over previous
//
#include <hip/hip_runtime.h>
#include <cstddef>

#define BB   8
#define NN   2048
#define CIN  64
#define COUT 64
#define KK   20
#define KSS  20
#define C2   128   // 2*CIN
#define NJ4  (C2 * KSS / 4)   // 640 float4 rows of the conv matrix
#define PPB  4                 // points per block (point_kernel)
#define JQ   (NJ4 / PPB)       // 160 j4-rows per wave in cooperative conv
#define NC   24                // fp32 candidate count for knn refine

// ---------------------------------------------------------------------------
// Prep: wT4[j4*64 + t] = conv_w[t][4*j4..+3]; mowT[c*64 + o] = mow[o][c]
// ---------------------------------------------------------------------------
__global__ __launch_bounds__(256) void prep_kernel(
    const float* __restrict__ cw, const float* __restrict__ mw,
    float4* __restrict__ wT4, float* __restrict__ mowT)
{
    int i = blockIdx.x * 256 + threadIdx.x;
    if (i < NJ4 * COUT) {
        int j4 = i >> 6, t = i & 63;
        const float* s = cw + (size_t)t * (C2 * KSS) + j4 * 4;
        wT4[i] = make_float4(s[0], s[1], s[2], s[3]);
    }
    if (i < COUT * CIN) {
        int o = i >> 6, c = i & 63;
        mowT[c * COUT + o] = mw[o * CIN + c];
    }
}

// ---------------------------------------------------------------------------
// KNN v3: phase 1 = fp32 packed-u64 selection of 24 candidates (top-3 lane
// cache, killmask rescan); phase 2 = fp64 exact re-rank via 32-lane bitonic
// sort (lex on (d2_bits, idx)). Membership fp64-exact, ties lowest-index.
// ---------------------------------------------------------------------------
__global__ __launch_bounds__(64) void knn_kernel(
    const float* __restrict__ x, unsigned short* __restrict__ idx_out)
{
    const unsigned long long SENT = 0xFFFFFFFFFFFFFFFFull;
    const int t = threadIdx.x;
    const int p = blockIdx.x;
    const int b = p >> 11;
    const int n = p & (NN - 1);

    const float* xb0 = x + (size_t)(b * 3 + 0) * NN;
    const float* xb1 = x + (size_t)(b * 3 + 1) * NN;
    const float* xb2 = x + (size_t)(b * 3 + 2) * NN;

    const float qx = xb0[n], qy = xb1[n], qz = xb2[n];

    float d2r[32];
#pragma unroll
    for (int j = 0; j < 32; ++j) {
        int m = t + 64 * j;
        float dx = xb0[m] - qx;
        float dy = xb1[m] - qy;
        float dz = xb2[m] - qz;
        d2r[j] = dx * dx + dy * dy + dz * dz;
    }

    // per-lane sorted top-3 packed cache (packed = d2bits<<32 | index;
    // u64 order == lex (d2, idx) for nonneg floats)
    unsigned long long c0 = SENT, c1 = SENT, c2 = SENT;
#pragma unroll
    for (int j = 0; j < 32; ++j) {
        unsigned long long pk =
            ((unsigned long long)__float_as_uint(d2r[j]) << 32)
            | (unsigned)(t + 64 * j);
        if (pk < c0)      { c2 = c1; c1 = c0; c0 = pk; }
        else if (pk < c1) { c2 = c1; c1 = pk; }
        else if (pk < c2) { c2 = pk; }
    }

    unsigned killmask = 0u;
    unsigned long long mypk = SENT;

    for (int k = 0; k < NC; ++k) {
        unsigned long long bp = c0;
#pragma unroll
        for (int off = 32; off > 0; off >>= 1) {
            unsigned long long op_ = __shfl_down(bp, off);
            if (op_ < bp) bp = op_;
        }
        bp = __shfl(bp, 0);
        if (t == k) mypk = bp;
        if (c0 == bp) {                           // unique owner lane
            killmask |= 1u << ((unsigned)(bp & 0xFFFFFFFFull) >> 6);
            c0 = c1; c1 = c2; c2 = SENT;
            if (c0 == SENT) {                     // rare rescan (top-3 cache)
#pragma unroll
                for (int j = 0; j < 32; ++j) {
                    if (!(killmask & (1u << j))) {
                        unsigned long long pk =
                            ((unsigned long long)__float_as_uint(d2r[j]) << 32)
                            | (unsigned)(t + 64 * j);
                        if (pk < c0)      { c2 = c1; c1 = c0; c0 = pk; }
                        else if (pk < c1) { c2 = c1; c1 = pk; }
                        else if (pk < c2) { c2 = pk; }
                    }
                }
            }
        }
    }

    // phase 2: fp64 exact re-rank of 24 candidates, 32-lane bitonic sort
    double dd = 1e300;
    int ci = 0x7fffffff;
    if (t < NC) {
        ci = (int)(mypk & 0xFFFFFFFFull);
        double dx = (double)xb0[ci] - (double)qx;
        double dy = (double)xb1[ci] - (double)qy;
        double dz = (double)xb2[ci] - (double)qz;
        dd = dx * dx + dy * dy + dz * dz;
    }
    unsigned long long db = __double_as_longlong(dd);  // nonneg -> monotone

#pragma unroll
    for (int size = 2; size <= 32; size <<= 1) {
#pragma unroll
        for (int stride = size >> 1; stride > 0; stride >>= 1) {
            unsigned long long odb = __shfl_xor(db, stride);
            int oci = __shfl_xor(ci, stride);
            bool up = ((t & size) == 0);
            bool takemin = (((t & stride) == 0) == up);
            bool oless = (odb < db) || (odb == db && oci < ci);
            if (takemin == oless) { db = odb; ci = oci; }
        }
    }

    if (t < KK) idx_out[(size_t)p * KK + t] = (unsigned short)ci;
}

// ---------------------------------------------------------------------------
// Per-point stage, 4 points/block. agg in LDS; conv cooperative across the
// 4 waves; red_s unioned onto perm_s storage (3 blocks/CU).
// ---------------------------------------------------------------------------
__global__ __launch_bounds__(256, 3) void point_kernel(
    const float* __restrict__ x,
    const float* __restrict__ feature,
    const float* __restrict__ kern,
    const float* __restrict__ pad,
    const float* __restrict__ mlp_w,
    const float* __restrict__ mlp_b,
    const float4* __restrict__ wT4,
    const float* __restrict__ conv_b,
    const float* __restrict__ mowT,
    const float* __restrict__ mob,
    const unsigned short* __restrict__ idx,
    float* __restrict__ out)
{
    __shared__ __align__(16) float agg_s[PPB][C2 * KSS];   // 40960 B
    __shared__ __align__(16) float u_s[PPB * KK * KSS];    // 6400 B (perm|red)
    __shared__ float xr_s[PPB][KK][3];
    __shared__ float xd_s[PPB][KK];
    __shared__ float xrep_s[PPB][3];
    __shared__ float colden_s[PPB][KSS];
    __shared__ float fcol_s[PPB][CIN];
    __shared__ int   nid_s[PPB][KK];

    float (*perm_s)[KK][KSS] = (float (*)[KK][KSS])u_s;
    float (*red_s)[PPB][64]  = (float (*)[PPB][64])u_s;

    const int tid  = threadIdx.x;
    const int w    = tid >> 6;
    const int lane = tid & 63;
    const int p    = blockIdx.x * PPB + w;
    const int b    = p >> 11;
    const int n    = p & (NN - 1);

    const float* xb0 = x + (size_t)(b * 3 + 0) * NN;
    const float* xb1 = x + (size_t)(b * 3 + 1) * NN;
    const float* xb2 = x + (size_t)(b * 3 + 2) * NN;

    if (lane < KK) nid_s[w][lane] = (int)idx[(size_t)p * KK + lane];
    fcol_s[w][lane] = feature[(size_t)(b * CIN + lane) * NN + n];
    __syncthreads();

    if (lane == 0) {
        int m0 = nid_s[w][0];
        xrep_s[w][0] = xb0[m0]; xrep_s[w][1] = xb1[m0]; xrep_s[w][2] = xb2[m0];
    }
    __syncthreads();
    if (lane < KK) {
        int m = nid_s[w][lane];
        float rx = xb0[m] - xrep_s[w][0];
        float ry = xb1[m] - xrep_s[w][1];
        float rz = xb2[m] - xrep_s[w][2];
        xr_s[w][lane][0] = rx; xr_s[w][lane][1] = ry; xr_s[w][lane][2] = rz;
        xd_s[w][lane] = sqrtf(rx * rx + ry * ry + rz * rz + 1e-12f);
    }
    __syncthreads();

    // ---- perm: relu -> colnorm -> square -> colnorm -> >0.1 ----
    for (int e = lane; e < KK * KSS; e += 64) {
        int k = e / KSS, m = e % KSS;
        float v = xr_s[w][k][0] * kern[0 * KSS + m]
                + xr_s[w][k][1] * kern[1 * KSS + m]
                + xr_s[w][k][2] * kern[2 * KSS + m]
                + pad[k * KSS + m];
        perm_s[w][k][m] = v > 0.0f ? v : 0.0f;
    }
    __syncthreads();
    if (lane < KSS) {
        float s = 0.0f;
        for (int k = 0; k < KK; ++k) s += perm_s[w][k][lane];
        colden_s[w][lane] = s + 1e-6f;
    }
    __syncthreads();
    for (int e = lane; e < KK * KSS; e += 64) {
        int k = e / KSS, m = e % KSS;
        float v = perm_s[w][k][m] / colden_s[w][m];
        perm_s[w][k][m] = v * v;
    }
    __syncthreads();
    if (lane < KSS) {
        float s = 0.0f;
        for (int k = 0; k < KK; ++k) s += perm_s[w][k][lane];
        colden_s[w][lane] = s + 1e-6f;
    }
    __syncthreads();
    for (int e = lane; e < KK * KSS; e += 64) {
        int k = e / KSS, m = e % KSS;
        float v = perm_s[w][k][m] / colden_s[w][m];
        perm_s[w][k][m] = v > 0.1f ? v : 0.0f;
    }
    __syncthreads();

    // ---- feats in registers ----
    float fg[KK], fm[KK];
#pragma unroll
    for (int k = 0; k < KK; ++k)
        fg[k] = feature[(size_t)(b * CIN + lane) * NN + nid_s[w][k]];
    {
        float w0 = mlp_w[lane * 7 + 0], w1 = mlp_w[lane * 7 + 1];
        float w2 = mlp_w[lane * 7 + 2], w3 = mlp_w[lane * 7 + 3];
        float w4 = mlp_w[lane * 7 + 4], w5 = mlp_w[lane * 7 + 5];
        float w6 = mlp_w[lane * 7 + 6];
        float bias = mlp_b[lane];
#pragma unroll
        for (int k = 0; k < KK; ++k) {
            fm[k] = xrep_s[w][0] * w0 + xrep_s[w][1] * w1 + xrep_s[w][2] * w2
                  + xr_s[w][k][0] * w3 + xr_s[w][k][1] * w4 + xr_s[w][k][2] * w5
                  + xd_s[w][k] * w6 + bias;
        }
    }

    // ---- agg rows c=lane, c=64+lane (perm's LAST use) ----
#pragma unroll
    for (int m = 0; m < KSS; ++m) {
        float s = 0.0f, s2 = 0.0f;
#pragma unroll
        for (int k = 0; k < KK; ++k) {
            float pv = perm_s[w][k][m];
            s  += fg[k] * pv;
            s2 += fm[k] * pv;
        }
        agg_s[w][lane * KSS + m]         = s;
        agg_s[w][(CIN + lane) * KSS + m] = s2;
    }
    __syncthreads();   // perm_s dead; red_s takes over

    // ---- cooperative conv: wave w -> j4 in [w*JQ,(w+1)*JQ) for ALL points --
    {
        float pa0 = 0.0f, pa1 = 0.0f, pa2 = 0.0f, pa3 = 0.0f;
        const float4* wp = wT4 + lane;
        const int j4lo = w * JQ, j4hi = j4lo + JQ;
#pragma unroll 2
        for (int j4 = j4lo; j4 < j4hi; ++j4) {
            float4 wv = wp[(size_t)j4 * 64];
            float4 a0 = *(const float4*)(&agg_s[0][j4 * 4]);
            float4 a1 = *(const float4*)(&agg_s[1][j4 * 4]);
            float4 a2 = *(const float4*)(&agg_s[2][j4 * 4]);
            float4 a3 = *(const float4*)(&agg_s[3][j4 * 4]);
            pa0 += wv.x * a0.x; pa0 += wv.y * a0.y; pa0 += wv.z * a0.z; pa0 += wv.w * a0.w;
            pa1 += wv.x * a1.x; pa1 += wv.y * a1.y; pa1 += wv.z * a1.z; pa1 += wv.w * a1.w;
            pa2 += wv.x * a2.x; pa2 += wv.y * a2.y; pa2 += wv.z * a2.z; pa2 += wv.w * a2.w;
            pa3 += wv.x * a3.x; pa3 += wv.y * a3.y; pa3 += wv.z * a3.z; pa3 += wv.w * a3.w;
        }
        red_s[0][w][lane] = pa0;
        red_s[1][w][lane] = pa1;
        red_s[2][w][lane] = pa2;
        red_s[3][w][lane] = pa3;
    }
    __syncthreads();

    // ---- wave w finalizes point w ----
    {
        float acc = conv_b[lane]
                  + ((red_s[w][0][lane] + red_s[w][1][lane])
                   + (red_s[w][2][lane] + red_s[w][3][lane]));
        for (int c = 0; c < CIN; ++c)
            acc += fcol_s[w][c] * mowT[c * COUT + lane];
        acc += mob[lane];
        out[(size_t)(b * COUT + lane) * NN + n] = acc;
    }
}

// ---------------------------------------------------------------------------
// BatchNorm per channel over (B,N), fp32 in-place. 64 blocks x 256.
// ---------------------------------------------------------------------------
__global__ __launch_bounds__(256) void bn_kernel(
    float* __restrict__ out,
    const float* __restrict__ gamma,
    const float* __restrict__ beta)
{
    const int o = blockIdx.x;
    __shared__ float s1[256], s2[256];
    __shared__ float mean_s, inv_s;

    float a = 0.0f, q = 0.0f;
    for (int i = threadIdx.x; i < BB * NN; i += 256) {
        int b = i >> 11, n = i & (NN - 1);
        float v = out[(size_t)(b * COUT + o) * NN + n];
        a += v; q += v * v;
    }
    s1[threadIdx.x] = a; s2[threadIdx.x] = q;
    __syncthreads();
    for (int s = 128; s > 0; s >>= 1) {
        if (threadIdx.x < s) {
            s1[threadIdx.x] += s1[threadIdx.x + s];
            s2[threadIdx.x] += s2[threadIdx.x + s];
        }
        __syncthreads();
    }
    if (threadIdx.x == 0) {
        const float M = (float)(BB * NN);
        float mean = s1[0] / M;
        float var  = s2[0] / M - mean * mean;
        if (var < 0.0f) var = 0.0f;
        mean_s = mean;
        inv_s  = 1.0f / sqrtf(var + 1e-5f);
    }
    __syncthreads();
    const float mean = mean_s, inv = inv_s;
    const float g = gamma[o], be = beta[o];
    for (int i = threadIdx.x; i < BB * NN; i += 256) {
        int b = i >> 11, n = i & (NN - 1);
        size_t ad = (size_t)(b * COUT + o) * NN + n;
        out[ad] = (out[ad] - mean) * inv * g + be;
    }
}

// ---------------------------------------------------------------------------
extern "C" void kernel_launch(void* const* d_in, const int* in_sizes, int n_in,
                              void* d_out, int out_size, void* d_ws, size_t ws_size,
                              hipStream_t stream)
{
    const float* x       = (const float*)d_in[0];
    const float* feature = (const float*)d_in[1];
    const float* kern    = (const float*)d_in[2];
    const float* pad     = (const float*)d_in[3];
    const float* mlp_w   = (const float*)d_in[4];
    const float* mlp_b   = (const float*)d_in[5];
    const float* conv_w  = (const float*)d_in[6];
    const float* conv_b  = (const float*)d_in[7];
    const float* mow     = (const float*)d_in[8];
    const float* mob     = (const float*)d_in[9];
    const float* gamma   = (const float*)d_in[10];
    const float* beta    = (const float*)d_in[11];

    char* wsp = (char*)d_ws;
    float4*         wT4     = (float4*)wsp;                        // 655360 B
    unsigned short* idx_buf = (unsigned short*)(wsp + 655360);     // 655360 B
    float*          mowT    = (float*)(wsp + 655360 * 2);          //  16384 B

    float* out = (float*)d_out;

    prep_kernel<<<(NJ4 * COUT + 255) / 256, 256, 0, stream>>>(conv_w, mow, wT4, mowT);
    knn_kernel<<<BB * NN, 64, 0, stream>>>(x, idx_buf);
    point_kernel<<<BB * NN / PPB, 256, 0, stream>>>(x, feature, kern, pad,
                                                    mlp_w, mlp_b, wT4, conv_b,
                                                    mowT, mob, idx_buf, out);
    bn_kernel<<<COUT, 256, 0, stream>>>(out, gamma, beta);
}

// Round 22
// 399.987 us; speedup vs baseline: 5.7649x; 1.0385x over previous
//
#include <hip/hip_runtime.h>
#include <cstddef>

#define BB   8
#define NN   2048
#define CIN  64
#define COUT 64
#define KK   20
#define KSS  20
#define C2   128   // 2*CIN
#define NJ4  (C2 * KSS / 4)   // 640 float4 rows of the conv matrix
#define PPB  4                 // points per block
#define JQ   (NJ4 / PPB)       // 160 j4-rows per wave in cooperative conv
#define NC   24                // fp32 candidate count for knn refine

// ---------------------------------------------------------------------------
// Prep: wT4[j4*64 + t] = conv_w[t][4*j4..+3]; mowT[c*64 + o] = mow[o][c]
// ---------------------------------------------------------------------------
__global__ __launch_bounds__(256) void prep_kernel(
    const float* __restrict__ cw, const float* __restrict__ mw,
    float4* __restrict__ wT4, float* __restrict__ mowT)
{
    int i = blockIdx.x * 256 + threadIdx.x;
    if (i < NJ4 * COUT) {
        int j4 = i >> 6, t = i & 63;
        const float* s = cw + (size_t)t * (C2 * KSS) + j4 * 4;
        wT4[i] = make_float4(s[0], s[1], s[2], s[3]);
    }
    if (i < COUT * CIN) {
        int o = i >> 6, c = i & 63;
        mowT[c * COUT + o] = mw[o * CIN + c];
    }
}

// ---------------------------------------------------------------------------
// FUSED kernel: phase 0 = per-wave KNN (fp32 packed top-24 + fp64 bitonic
// re-rank; wave-local, no barriers), then perm/feats/agg/cooperative-conv.
// 4 points/block, 3 blocks/CU. KNN's VALU/global phase overlaps other
// blocks' LDS-bound conv phase on the same CU.
// ---------------------------------------------------------------------------
__global__ __launch_bounds__(256, 3) void point_kernel(
    const float* __restrict__ x,
    const float* __restrict__ feature,
    const float* __restrict__ kern,
    const float* __restrict__ pad,
    const float* __restrict__ mlp_w,
    const float* __restrict__ mlp_b,
    const float4* __restrict__ wT4,
    const float* __restrict__ conv_b,
    const float* __restrict__ mowT,
    const float* __restrict__ mob,
    float* __restrict__ out)
{
    __shared__ __align__(16) float agg_s[PPB][C2 * KSS];   // 40960 B
    __shared__ __align__(16) float u_s[PPB * KK * KSS];    // 6400 B (perm|red)
    __shared__ float xr_s[PPB][KK][3];
    __shared__ float xd_s[PPB][KK];
    __shared__ float xrep_s[PPB][3];
    __shared__ float colden_s[PPB][KSS];
    __shared__ float fcol_s[PPB][CIN];
    __shared__ int   nid_s[PPB][KK];

    float (*perm_s)[KK][KSS] = (float (*)[KK][KSS])u_s;
    float (*red_s)[PPB][64]  = (float (*)[PPB][64])u_s;

    const int tid  = threadIdx.x;
    const int w    = tid >> 6;
    const int lane = tid & 63;
    const int p    = blockIdx.x * PPB + w;
    const int b    = p >> 11;
    const int n    = p & (NN - 1);

    const float* xb0 = x + (size_t)(b * 3 + 0) * NN;
    const float* xb1 = x + (size_t)(b * 3 + 1) * NN;
    const float* xb2 = x + (size_t)(b * 3 + 2) * NN;

    // ================= phase 0: KNN (wave-local, verified v3) =============
    {
        const unsigned long long SENT = 0xFFFFFFFFFFFFFFFFull;
        const float qx = xb0[n], qy = xb1[n], qz = xb2[n];

        float d2r[32];
#pragma unroll
        for (int j = 0; j < 32; ++j) {
            int m = lane + 64 * j;
            float dx = xb0[m] - qx;
            float dy = xb1[m] - qy;
            float dz = xb2[m] - qz;
            d2r[j] = dx * dx + dy * dy + dz * dz;
        }

        unsigned long long c0 = SENT, c1 = SENT, c2 = SENT;
#pragma unroll
        for (int j = 0; j < 32; ++j) {
            unsigned long long pk =
                ((unsigned long long)__float_as_uint(d2r[j]) << 32)
                | (unsigned)(lane + 64 * j);
            if (pk < c0)      { c2 = c1; c1 = c0; c0 = pk; }
            else if (pk < c1) { c2 = c1; c1 = pk; }
            else if (pk < c2) { c2 = pk; }
        }

        unsigned killmask = 0u;
        unsigned long long mypk = SENT;
        for (int k = 0; k < NC; ++k) {
            unsigned long long bp = c0;
#pragma unroll
            for (int off = 32; off > 0; off >>= 1) {
                unsigned long long op_ = __shfl_down(bp, off);
                if (op_ < bp) bp = op_;
            }
            bp = __shfl(bp, 0);
            if (lane == k) mypk = bp;
            if (c0 == bp) {
                killmask |= 1u << ((unsigned)(bp & 0xFFFFFFFFull) >> 6);
                c0 = c1; c1 = c2; c2 = SENT;
                if (c0 == SENT) {
#pragma unroll
                    for (int j = 0; j < 32; ++j) {
                        if (!(killmask & (1u << j))) {
                            unsigned long long pk =
                                ((unsigned long long)__float_as_uint(d2r[j]) << 32)
                                | (unsigned)(lane + 64 * j);
                            if (pk < c0)      { c2 = c1; c1 = c0; c0 = pk; }
                            else if (pk < c1) { c2 = c1; c1 = pk; }
                            else if (pk < c2) { c2 = pk; }
                        }
                    }
                }
            }
        }

        double dd = 1e300;
        int ci = 0x7fffffff;
        if (lane < NC) {
            ci = (int)(mypk & 0xFFFFFFFFull);
            double dx = (double)xb0[ci] - (double)qx;
            double dy = (double)xb1[ci] - (double)qy;
            double dz = (double)xb2[ci] - (double)qz;
            dd = dx * dx + dy * dy + dz * dz;
        }
        unsigned long long db = __double_as_longlong(dd);
#pragma unroll
        for (int size = 2; size <= 32; size <<= 1) {
#pragma unroll
            for (int stride = size >> 1; stride > 0; stride >>= 1) {
                unsigned long long odb = __shfl_xor(db, stride);
                int oci = __shfl_xor(ci, stride);
                bool up = ((lane & size) == 0);
                bool takemin = (((lane & stride) == 0) == up);
                bool oless = (odb < db) || (odb == db && oci < ci);
                if (takemin == oless) { db = odb; ci = oci; }
            }
        }
        if (lane < KK) nid_s[w][lane] = ci;     // same-wave producer/consumer
    }

    // ================= per-point pipeline (as r21) ========================
    fcol_s[w][lane] = feature[(size_t)(b * CIN + lane) * NN + n];

    if (lane == 0) {
        int m0 = nid_s[w][0];
        xrep_s[w][0] = xb0[m0]; xrep_s[w][1] = xb1[m0]; xrep_s[w][2] = xb2[m0];
    }
    // nid_s/xrep_s written and read by the same wave: no cross-wave hazard.
    if (lane < KK) {
        int m = nid_s[w][lane];
        float rx = xb0[m] - xrep_s[w][0];
        float ry = xb1[m] - xrep_s[w][1];
        float rz = xb2[m] - xrep_s[w][2];
        xr_s[w][lane][0] = rx; xr_s[w][lane][1] = ry; xr_s[w][lane][2] = rz;
        xd_s[w][lane] = sqrtf(rx * rx + ry * ry + rz * rz + 1e-12f);
    }
    __syncthreads();

    // ---- perm: relu -> colnorm -> square -> colnorm -> >0.1 ----
    for (int e = lane; e < KK * KSS; e += 64) {
        int k = e / KSS, m = e % KSS;
        float v = xr_s[w][k][0] * kern[0 * KSS + m]
                + xr_s[w][k][1] * kern[1 * KSS + m]
                + xr_s[w][k][2] * kern[2 * KSS + m]
                + pad[k * KSS + m];
        perm_s[w][k][m] = v > 0.0f ? v : 0.0f;
    }
    __syncthreads();
    if (lane < KSS) {
        float s = 0.0f;
        for (int k = 0; k < KK; ++k) s += perm_s[w][k][lane];
        colden_s[w][lane] = s + 1e-6f;
    }
    __syncthreads();
    for (int e = lane; e < KK * KSS; e += 64) {
        int k = e / KSS, m = e % KSS;
        float v = perm_s[w][k][m] / colden_s[w][m];
        perm_s[w][k][m] = v * v;
    }
    __syncthreads();
    if (lane < KSS) {
        float s = 0.0f;
        for (int k = 0; k < KK; ++k) s += perm_s[w][k][lane];
        colden_s[w][lane] = s + 1e-6f;
    }
    __syncthreads();
    for (int e = lane; e < KK * KSS; e += 64) {
        int k = e / KSS, m = e % KSS;
        float v = perm_s[w][k][m] / colden_s[w][m];
        perm_s[w][k][m] = v > 0.1f ? v : 0.0f;
    }
    __syncthreads();

    // ---- feats in registers ----
    float fg[KK], fm[KK];
#pragma unroll
    for (int k = 0; k < KK; ++k)
        fg[k] = feature[(size_t)(b * CIN + lane) * NN + nid_s[w][k]];
    {
        float w0 = mlp_w[lane * 7 + 0], w1 = mlp_w[lane * 7 + 1];
        float w2 = mlp_w[lane * 7 + 2], w3 = mlp_w[lane * 7 + 3];
        float w4 = mlp_w[lane * 7 + 4], w5 = mlp_w[lane * 7 + 5];
        float w6 = mlp_w[lane * 7 + 6];
        float bias = mlp_b[lane];
#pragma unroll
        for (int k = 0; k < KK; ++k) {
            fm[k] = xrep_s[w][0] * w0 + xrep_s[w][1] * w1 + xrep_s[w][2] * w2
                  + xr_s[w][k][0] * w3 + xr_s[w][k][1] * w4 + xr_s[w][k][2] * w5
                  + xd_s[w][k] * w6 + bias;
        }
    }

    // ---- agg rows c=lane, c=64+lane (perm's LAST use) ----
#pragma unroll
    for (int m = 0; m < KSS; ++m) {
        float s = 0.0f, s2 = 0.0f;
#pragma unroll
        for (int k = 0; k < KK; ++k) {
            float pv = perm_s[w][k][m];
            s  += fg[k] * pv;
            s2 += fm[k] * pv;
        }
        agg_s[w][lane * KSS + m]         = s;
        agg_s[w][(CIN + lane) * KSS + m] = s2;
    }
    __syncthreads();   // perm_s dead; red_s takes over

    // ---- cooperative conv ----
    {
        float pa0 = 0.0f, pa1 = 0.0f, pa2 = 0.0f, pa3 = 0.0f;
        const float4* wp = wT4 + lane;
        const int j4lo = w * JQ, j4hi = j4lo + JQ;
#pragma unroll 2
        for (int j4 = j4lo; j4 < j4hi; ++j4) {
            float4 wv = wp[(size_t)j4 * 64];
            float4 a0 = *(const float4*)(&agg_s[0][j4 * 4]);
            float4 a1 = *(const float4*)(&agg_s[1][j4 * 4]);
            float4 a2 = *(const float4*)(&agg_s[2][j4 * 4]);
            float4 a3 = *(const float4*)(&agg_s[3][j4 * 4]);
            pa0 += wv.x * a0.x; pa0 += wv.y * a0.y; pa0 += wv.z * a0.z; pa0 += wv.w * a0.w;
            pa1 += wv.x * a1.x; pa1 += wv.y * a1.y; pa1 += wv.z * a1.z; pa1 += wv.w * a1.w;
            pa2 += wv.x * a2.x; pa2 += wv.y * a2.y; pa2 += wv.z * a2.z; pa2 += wv.w * a2.w;
            pa3 += wv.x * a3.x; pa3 += wv.y * a3.y; pa3 += wv.z * a3.z; pa3 += wv.w * a3.w;
        }
        red_s[0][w][lane] = pa0;
        red_s[1][w][lane] = pa1;
        red_s[2][w][lane] = pa2;
        red_s[3][w][lane] = pa3;
    }
    __syncthreads();

    // ---- wave w finalizes point w ----
    {
        float acc = conv_b[lane]
                  + ((red_s[w][0][lane] + red_s[w][1][lane])
                   + (red_s[w][2][lane] + red_s[w][3][lane]));
        for (int c = 0; c < CIN; ++c)
            acc += fcol_s[w][c] * mowT[c * COUT + lane];
        acc += mob[lane];
        out[(size_t)(b * COUT + lane) * NN + n] = acc;
    }
}

// ---------------------------------------------------------------------------
// BatchNorm per channel over (B,N), fp32 in-place. 64 blocks x 256.
// ---------------------------------------------------------------------------
__global__ __launch_bounds__(256) void bn_kernel(
    float* __restrict__ out,
    const float* __restrict__ gamma,
    const float* __restrict__ beta)
{
    const int o = blockIdx.x;
    __shared__ float s1[256], s2[256];
    __shared__ float mean_s, inv_s;

    float a = 0.0f, q = 0.0f;
    for (int i = threadIdx.x; i < BB * NN; i += 256) {
        int b = i >> 11, n = i & (NN - 1);
        float v = out[(size_t)(b * COUT + o) * NN + n];
        a += v; q += v * v;
    }
    s1[threadIdx.x] = a; s2[threadIdx.x] = q;
    __syncthreads();
    for (int s = 128; s > 0; s >>= 1) {
        if (threadIdx.x < s) {
            s1[threadIdx.x] += s1[threadIdx.x + s];
            s2[threadIdx.x] += s2[threadIdx.x + s];
        }
        __syncthreads();
    }
    if (threadIdx.x == 0) {
        const float M = (float)(BB * NN);
        float mean = s1[0] / M;
        float var  = s2[0] / M - mean * mean;
        if (var < 0.0f) var = 0.0f;
        mean_s = mean;
        inv_s  = 1.0f / sqrtf(var + 1e-5f);
    }
    __syncthreads();
    const float mean = mean_s, inv = inv_s;
    const float g = gamma[o], be = beta[o];
    for (int i = threadIdx.x; i < BB * NN; i += 256) {
        int b = i >> 11, n = i & (NN - 1);
        size_t ad = (size_t)(b * COUT + o) * NN + n;
        out[ad] = (out[ad] - mean) * inv * g + be;
    }
}

// ---------------------------------------------------------------------------
extern "C" void kernel_launch(void* const* d_in, const int* in_sizes, int n_in,
                              void* d_out, int out_size, void* d_ws, size_t ws_size,
                              hipStream_t stream)
{
    const float* x       = (const float*)d_in[0];
    const float* feature = (const float*)d_in[1];
    const float* kern    = (const float*)d_in[2];
    const float* pad     = (const float*)d_in[3];
    const float* mlp_w   = (const float*)d_in[4];
    const float* mlp_b   = (const float*)d_in[5];
    const float* conv_w  = (const float*)d_in[6];
    const float* conv_b  = (const float*)d_in[7];
    const float* mow     = (const float*)d_in[8];
    const float* mob     = (const float*)d_in[9];
    const float* gamma   = (const float*)d_in[10];
    const float* beta    = (const float*)d_in[11];

    char* wsp = (char*)d_ws;
    float4* wT4  = (float4*)wsp;                        // 655360 B
    float*  mowT = (float*)(wsp + 655360);              //  16384 B

    float* out = (float*)d_out;

    prep_kernel<<<(NJ4 * COUT + 255) / 256, 256, 0, stream>>>(conv_w, mow, wT4, mowT);
    point_kernel<<<BB * NN / PPB, 256, 0, stream>>>(x, feature, kern, pad,
                                                    mlp_w, mlp_b, wT4, conv_b,
                                                    mowT, mob, out);
    bn_kernel<<<COUT, 256, 0, stream>>>(out, gamma, beta);
}